// Round 2
// baseline (4509.289 us; speedup 1.0000x reference)
//
#include <hip/hip_runtime.h>
#include <hip/hip_bf16.h>
#include <stdint.h>

#define GRIDN 48
#define F 2304
#define C 128
#define H 8
#define DH 16
#define NB 2          // batch (meshes)
#define WID 256
#define NLV 49        // BFS levels for GRID=48, anchor at (24,24)

typedef __hip_bfloat16 bf16;

__device__ __forceinline__ float b2f(bf16 v) { return __bfloat162float(v); }

// ---------------------------------------------------------------- K-1: input dtype detector
__global__ void k_detect(const void* __restrict__ x, int* __restrict__ flag) {
    __shared__ int bad;
    if (threadIdx.x == 0) bad = 0;
    __syncthreads();
    const bf16* xb = (const bf16*)x;
    int insane = 0;
    #pragma unroll
    for (int i = 0; i < 8; ++i) {
        float v = b2f(xb[threadIdx.x * 8 + i]);
        if (!(fabsf(v) < 1e10f)) insane = 1;   // catches NaN/Inf/huge
    }
    if (insane) atomicOr(&bad, 1);
    __syncthreads();
    if (threadIdx.x == 0) *flag = bad;
}

// ---------------------------------------------------------------- K0: BFS-ring permutation of the key axis
// Also zero-inits the grid-barrier counters (runs before k_flood every replay).
__global__ void k_perm(int* __restrict__ permIdx, int* __restrict__ bar) {
    __shared__ int cnt[NLV], start[NLV];
    int t = threadIdx.x;
    if (t < NLV) cnt[t] = 0;
    if (t == 0) { bar[0] = 0; bar[1] = 0; }
    __syncthreads();
    for (int f = t; f < F; f += 256) {
        int d = abs(f / GRIDN - GRIDN / 2) + abs(f % GRIDN - GRIDN / 2);
        atomicAdd(&cnt[d], 1);
    }
    __syncthreads();
    if (t == 0) {
        int s = 0;
        for (int l = 0; l < NLV; ++l) { start[l] = s; s += cnt[l]; }
    }
    __syncthreads();
    for (int f = t; f < F; f += 256) {
        int d = abs(f / GRIDN - GRIDN / 2) + abs(f % GRIDN - GRIDN / 2);
        permIdx[f] = atomicAdd(&start[d], 1);
    }
}

// ---------------------------------------------------------------- K0b: convert all weights/biases to fp32
struct WSeg { const void* src; int off; int cnt; };
struct WSegs { WSeg s[14]; };

__global__ void k_convert(WSegs segs, const int* __restrict__ flag,
                          float* __restrict__ dst, int total) {
    int i = blockIdx.x * blockDim.x + threadIdx.x;
    if (i >= total) return;
    bool f32 = (*flag != 0);
    #pragma unroll 1
    for (int j = 0; j < 14; ++j) {
        int off = segs.s[j].off, cnt = segs.s[j].cnt;
        if (i >= off && i < off + cnt) {
            int k = i - off;
            dst[i] = f32 ? ((const float*)segs.s[j].src)[k]
                         : b2f(((const bf16*)segs.s[j].src)[k]);
            return;
        }
    }
}

// ---------------------------------------------------------------- K1: x[B,C,F] -> cur[B,F,C] f32
__global__ void k_transpose_in(const void* __restrict__ x, const int* __restrict__ flag,
                               float* __restrict__ cur) {
    __shared__ float tile[32][33];
    bool f32 = (*flag != 0);
    int b = blockIdx.z;
    int f0 = blockIdx.x * 32, c0 = blockIdx.y * 32;
    int tx = threadIdx.x, ty = threadIdx.y;            // 32 x 8
    #pragma unroll
    for (int i = 0; i < 4; ++i) {
        int c = c0 + ty + i * 8;
        size_t idx = ((size_t)b * C + c) * F + f0 + tx;
        tile[ty + i * 8][tx] = f32 ? ((const float*)x)[idx] : b2f(((const bf16*)x)[idx]);
    }
    __syncthreads();
    #pragma unroll
    for (int i = 0; i < 4; ++i) {
        int f = f0 + ty + i * 8;
        cur[((size_t)b * F + f) * C + c0 + tx] = tile[tx][ty + i * 8];
    }
}

// ---------------------------------------------------------------- K2: init projections.
__global__ __launch_bounds__(128) void k_proj_init(
        const float* __restrict__ cur, const int* __restrict__ permIdx,
        const float* __restrict__ Wq, const float* __restrict__ Wk, const float* __restrict__ Wv,
        float* __restrict__ qh, float* __restrict__ khT, float* __restrict__ vhT) {
    __shared__ float rows[8][C];
    int r0 = blockIdx.x * 8;
    int tid = threadIdx.x;  // 0..127 = output channel
    #pragma unroll
    for (int r = 0; r < 8; ++r) rows[r][tid] = cur[(size_t)(r0 + r) * C + tid];
    __syncthreads();
    float aq[8], ak[8], av[8];
    #pragma unroll
    for (int r = 0; r < 8; ++r) { aq[r] = 0.f; ak[r] = 0.f; av[r] = 0.f; }
    for (int k = 0; k < C; ++k) {
        float wq = Wq[k * C + tid];
        float wk = Wk[k * C + tid];
        float wv = Wv[k * C + tid];
        #pragma unroll
        for (int r = 0; r < 8; ++r) {
            float xv = rows[r][k];
            aq[r] = fmaf(xv, wq, aq[r]);
            ak[r] = fmaf(xv, wk, ak[r]);
            av[r] = fmaf(xv, wv, av[r]);
        }
    }
    const float scale = 0.25f;  // 1/sqrt(DH)
    #pragma unroll
    for (int r = 0; r < 8; ++r) {
        int grow = r0 + r;
        int mesh = grow / F, face = grow % F;
        int p = permIdx[face];
        qh[(size_t)grow * C + tid] = aq[r] * scale;
        khT[((size_t)mesh * C + tid) * F + p] = ak[r];
        vhT[((size_t)mesh * C + tid) * F + p] = av[r];
    }
}

// ---------------------------------------------------------------- K2b: frozen copies khT0/vhT0
__global__ void k_copy(const float4* __restrict__ src, float4* __restrict__ dst, int n4) {
    int i = blockIdx.x * blockDim.x + threadIdx.x;
    if (i < n4) dst[i] = src[i];
}

// ---------------------------------------------------------------- manual grid barrier
// Sense-reversing barrier on device-scope atomics (cross-XCD correct per G12/m20).
// __threadfence() on both sides: release all data writes before arrival, invalidate
// stale L1/L2 after departure (per-XCD L2s are not HW-coherent).
__device__ __forceinline__ void grid_barrier(int nblk, int* __restrict__ cnt,
                                             int* __restrict__ gen) {
    __threadfence();
    __syncthreads();
    if (threadIdx.x == 0) {
        int g = __hip_atomic_load(gen, __ATOMIC_SEQ_CST, __HIP_MEMORY_SCOPE_AGENT);
        int a = __hip_atomic_fetch_add(cnt, 1, __ATOMIC_SEQ_CST, __HIP_MEMORY_SCOPE_AGENT);
        if (a == nblk - 1) {
            __hip_atomic_store(cnt, 0, __ATOMIC_SEQ_CST, __HIP_MEMORY_SCOPE_AGENT);
            __hip_atomic_fetch_add(gen, 1, __ATOMIC_SEQ_CST, __HIP_MEMORY_SCOPE_AGENT);
        } else {
            while (__hip_atomic_load(gen, __ATOMIC_SEQ_CST, __HIP_MEMORY_SCOPE_AGENT) == g)
                __builtin_amdgcn_s_sleep(2);
        }
    }
    __syncthreads();
    __threadfence();
}

// ---------------------------------------------------------------- K3: ALL BFS levels, one plain kernel.
// grid = gmax (= 2*max_nspair <= ~96) blocks, all co-resident on 256 CUs by construction.
// Inner per-level algorithm identical to the verified multi-launch kernel.
struct Rings { int v[NLV + 1]; };

__global__ __launch_bounds__(256) void k_flood(
        int Bd, int nblk, Rings rings,
        const int* __restrict__ levels, const int* __restrict__ permIdx,
        const float* __restrict__ qh_all, float* __restrict__ cur,
        float* __restrict__ khT, float* __restrict__ vhT,
        const float* __restrict__ khT0, const float* __restrict__ vhT0,
        const float* __restrict__ Wk, const float* __restrict__ Wv,
        const float* __restrict__ Wo, int* __restrict__ bar) {
    int bx = blockIdx.x;
    int mesh = bx & 1;                 // parity swizzle: mesh per XCD-parity
    int spair = bx >> 1;
    int tid = threadIdx.x;

    __shared__ float sQh[2][C], sQ[2][C], sRed[2][C], sNew[C];
    __shared__ float sL[2][H];

    for (int lv = 0; lv < NLV; ++lv) {
        int rs = rings.v[lv], re = rings.v[lv + 1];
        int ring = re - rs;
        int nspair = (ring + 1) / 2;
        if (spair < nspair) {
            int s0 = spair * 2, s1 = s0 + 1;
            int face0 = (s0 < Bd) ? levels[lv * Bd + s0] : F;
            int face1 = (s1 < Bd) ? levels[lv * Bd + s1] : F;
            bool a0 = (face0 >= 0 && face0 < F), a1 = (face1 >= 0 && face1 < F);

            size_t row0 = ((size_t)mesh * F + face0) * C;
            size_t row1 = ((size_t)mesh * F + face1) * C;
            if (tid < C) {
                if (a0) { sQ[0][tid] = cur[row0 + tid]; sQh[0][tid] = qh_all[row0 + tid]; }
                else    { sQ[0][tid] = 0.f; sQh[0][tid] = 0.f; }
            } else {
                int c = tid - C;
                if (a1) { sQ[1][c] = cur[row1 + c]; sQh[1][c] = qh_all[row1 + c]; }
                else    { sQ[1][c] = 0.f; sQh[1][c] = 0.f; }
            }
            __syncthreads();

            int head = tid >> 5, sub = tid & 31;
            float q0[DH], q1[DH];
            #pragma unroll
            for (int d = 0; d < DH; ++d) { q0[d] = sQh[0][head * DH + d]; q1[d] = sQh[1][head * DH + d]; }

            const float* Kb = khT  + ((size_t)mesh * C + head * DH) * F;
            const float* Vb = vhT  + ((size_t)mesh * C + head * DH) * F;
            const float* Kz = khT0 + ((size_t)mesh * C + head * DH) * F;
            const float* Vz = vhT0 + ((size_t)mesh * C + head * DH) * F;

            float m0 = -1e30f, l0 = 0.f, m1 = -1e30f, l1 = 0.f;
            float acc0[DH], acc1[DH];
            #pragma unroll
            for (int d = 0; d < DH; ++d) { acc0[d] = 0.f; acc1[d] = 0.f; }

            for (int base = 0; base < F; base += 128) {
                int p4 = base + 4 * sub;
                float sx0 = 0, sy0 = 0, sz0 = 0, sw0 = 0;
                float sx1 = 0, sy1 = 0, sz1 = 0, sw1 = 0;
                bool grp = (base < re) && (base + 128 > rs);    // block-uniform: stale interval overlap
                int t0 = 0, t1 = 0, t2 = 0, t3 = 0;
                if (!grp) {
                    #pragma unroll
                    for (int d = 0; d < DH; ++d) {
                        float4 kk = *(const float4*)(Kb + d * F + p4);
                        float a = q0[d], b = q1[d];
                        sx0 = fmaf(a, kk.x, sx0); sy0 = fmaf(a, kk.y, sy0);
                        sz0 = fmaf(a, kk.z, sz0); sw0 = fmaf(a, kk.w, sw0);
                        sx1 = fmaf(b, kk.x, sx1); sy1 = fmaf(b, kk.y, sy1);
                        sz1 = fmaf(b, kk.z, sz1); sw1 = fmaf(b, kk.w, sw1);
                    }
                } else {
                    t0 = (p4 >= rs && p4 < re); t1 = (p4 + 1 >= rs && p4 + 1 < re);
                    t2 = (p4 + 2 >= rs && p4 + 2 < re); t3 = (p4 + 3 >= rs && p4 + 3 < re);
                    #pragma unroll
                    for (int d = 0; d < DH; ++d) {
                        float4 kk = *(const float4*)(Kb + d * F + p4);
                        float4 kz = *(const float4*)(Kz + d * F + p4);
                        kk.x = t0 ? kz.x : kk.x; kk.y = t1 ? kz.y : kk.y;
                        kk.z = t2 ? kz.z : kk.z; kk.w = t3 ? kz.w : kk.w;
                        float a = q0[d], b = q1[d];
                        sx0 = fmaf(a, kk.x, sx0); sy0 = fmaf(a, kk.y, sy0);
                        sz0 = fmaf(a, kk.z, sz0); sw0 = fmaf(a, kk.w, sw0);
                        sx1 = fmaf(b, kk.x, sx1); sy1 = fmaf(b, kk.y, sy1);
                        sz1 = fmaf(b, kk.z, sz1); sw1 = fmaf(b, kk.w, sw1);
                    }
                }
                // online softmax update, query 0
                float mx0 = fmaxf(fmaxf(sx0, sy0), fmaxf(sz0, sw0));
                float mn0 = fmaxf(m0, mx0);
                float c0 = __expf(m0 - mn0);
                float px0 = __expf(sx0 - mn0), py0 = __expf(sy0 - mn0);
                float pz0 = __expf(sz0 - mn0), pw0 = __expf(sw0 - mn0);
                l0 = fmaf(l0, c0, px0 + py0 + pz0 + pw0);
                m0 = mn0;
                // query 1
                float mx1 = fmaxf(fmaxf(sx1, sy1), fmaxf(sz1, sw1));
                float mn1 = fmaxf(m1, mx1);
                float c1e = __expf(m1 - mn1);
                float px1 = __expf(sx1 - mn1), py1 = __expf(sy1 - mn1);
                float pz1 = __expf(sz1 - mn1), pw1 = __expf(sw1 - mn1);
                l1 = fmaf(l1, c1e, px1 + py1 + pz1 + pw1);
                m1 = mn1;
                if (!grp) {
                    #pragma unroll
                    for (int d = 0; d < DH; ++d) {
                        float4 vv = *(const float4*)(Vb + d * F + p4);
                        float w0 = fmaf(px0, vv.x, fmaf(py0, vv.y, fmaf(pz0, vv.z, pw0 * vv.w)));
                        float w1 = fmaf(px1, vv.x, fmaf(py1, vv.y, fmaf(pz1, vv.z, pw1 * vv.w)));
                        acc0[d] = fmaf(acc0[d], c0, w0);
                        acc1[d] = fmaf(acc1[d], c1e, w1);
                    }
                } else {
                    #pragma unroll
                    for (int d = 0; d < DH; ++d) {
                        float4 vv = *(const float4*)(Vb + d * F + p4);
                        float4 vz = *(const float4*)(Vz + d * F + p4);
                        vv.x = t0 ? vz.x : vv.x; vv.y = t1 ? vz.y : vv.y;
                        vv.z = t2 ? vz.z : vv.z; vv.w = t3 ? vz.w : vv.w;
                        float w0 = fmaf(px0, vv.x, fmaf(py0, vv.y, fmaf(pz0, vv.z, pw0 * vv.w)));
                        float w1 = fmaf(px1, vv.x, fmaf(py1, vv.y, fmaf(pz1, vv.z, pw1 * vv.w)));
                        acc0[d] = fmaf(acc0[d], c0, w0);
                        acc1[d] = fmaf(acc1[d], c1e, w1);
                    }
                }
            }

            // merge 32 per-lane online-softmax states per head
            #pragma unroll
            for (int w = 16; w >= 1; w >>= 1) {
                float mo = __shfl_xor(m0, w), lo = __shfl_xor(l0, w);
                float mn = fmaxf(m0, mo);
                float ca = __expf(m0 - mn), cb = __expf(mo - mn);
                l0 = l0 * ca + lo * cb;
                #pragma unroll
                for (int d = 0; d < DH; ++d) {
                    float ao = __shfl_xor(acc0[d], w);
                    acc0[d] = acc0[d] * ca + ao * cb;
                }
                m0 = mn;
                mo = __shfl_xor(m1, w); lo = __shfl_xor(l1, w);
                mn = fmaxf(m1, mo);
                ca = __expf(m1 - mn); cb = __expf(mo - mn);
                l1 = l1 * ca + lo * cb;
                #pragma unroll
                for (int d = 0; d < DH; ++d) {
                    float ao = __shfl_xor(acc1[d], w);
                    acc1[d] = acc1[d] * ca + ao * cb;
                }
                m1 = mn;
            }
            if (sub == 0) {
                sL[0][head] = l0; sL[1][head] = l1;
                #pragma unroll
                for (int d = 0; d < DH; ++d) {
                    sRed[0][head * DH + d] = acc0[d];
                    sRed[1][head * DH + d] = acc1[d];
                }
            }
            __syncthreads();
            if (tid < C) sRed[0][tid] = sRed[0][tid] / sL[0][tid >> 4];
            else { int c = tid - C; sRed[1][c] = sRed[1][c] / sL[1][c >> 4]; }
            __syncthreads();

            // epilogue per query: out-proj + resid, then K/V column refresh (ring-lv cols;
            // same-level readers take them from khT0/vhT0, so the eager write is race-free)
            #pragma unroll 1
            for (int j = 0; j < 2; ++j) {
                bool act = j == 0 ? a0 : a1;
                if (!act) continue;
                size_t rowj = j == 0 ? row0 : row1;
                int facej = j == 0 ? face0 : face1;
                if (tid < C) {
                    float o = 0.f;
                    for (int k = 0; k < C; ++k) o = fmaf(sRed[j][k], Wo[k * C + tid], o);
                    float nv = sQ[j][tid] + o;
                    sNew[tid] = nv;
                    cur[rowj + tid] = nv;
                }
                __syncthreads();
                int p = permIdx[facej];
                if (tid < C) {
                    float a = 0.f;
                    for (int k = 0; k < C; ++k) a = fmaf(sNew[k], Wk[k * C + tid], a);
                    khT[((size_t)mesh * C + tid) * F + p] = a;
                } else {
                    int c = tid - C;
                    float a = 0.f;
                    for (int k = 0; k < C; ++k) a = fmaf(sNew[k], Wv[k * C + c], a);
                    vhT[((size_t)mesh * C + c) * F + p] = a;
                }
                __syncthreads();
            }
        }
        if (lv != NLV - 1) grid_barrier(nblk, bar, bar + 1);
    }
}

// ---------------------------------------------------------------- K4: 5-layer MLP + sigmoid (8 rows/block)
__global__ __launch_bounds__(256) void k_mlp(
        const float* __restrict__ cur,
        const float* __restrict__ W1, const float* __restrict__ b1,
        const float* __restrict__ W2, const float* __restrict__ b2,
        const float* __restrict__ W3, const float* __restrict__ b3,
        const float* __restrict__ W4, const float* __restrict__ b4,
        const float* __restrict__ W5, const float* __restrict__ b5,
        float* __restrict__ out_scores) {
    __shared__ float sIn[8][C];
    __shared__ float sA[8][WID];
    __shared__ float sB[8][WID];
    int tid = threadIdx.x;                        // 0..255
    int r0 = blockIdx.x * 8;
    for (int i = tid; i < 8 * C; i += 256) sIn[i >> 7][i & 127] = cur[(size_t)r0 * C + i];
    __syncthreads();
    {
        float a[8];
        #pragma unroll
        for (int r = 0; r < 8; ++r) a[r] = 0.f;
        for (int k = 0; k < C; ++k) {
            float w = W1[k * WID + tid];
            #pragma unroll
            for (int r = 0; r < 8; ++r) a[r] = fmaf(sIn[r][k], w, a[r]);
        }
        float bias = b1[tid];
        #pragma unroll
        for (int r = 0; r < 8; ++r) sA[r][tid] = fmaxf(a[r] + bias, 0.f);
    }
    __syncthreads();
    {
        float a[8];
        #pragma unroll
        for (int r = 0; r < 8; ++r) a[r] = 0.f;
        for (int k = 0; k < WID; ++k) {
            float w = W2[k * WID + tid];
            #pragma unroll
            for (int r = 0; r < 8; ++r) a[r] = fmaf(sA[r][k], w, a[r]);
        }
        float bias = b2[tid];
        #pragma unroll
        for (int r = 0; r < 8; ++r) sB[r][tid] = fmaxf(a[r] + bias, 0.f);
    }
    __syncthreads();
    {
        float a[8];
        #pragma unroll
        for (int r = 0; r < 8; ++r) a[r] = 0.f;
        for (int k = 0; k < WID; ++k) {
            float w = W3[k * WID + tid];
            #pragma unroll
            for (int r = 0; r < 8; ++r) a[r] = fmaf(sB[r][k], w, a[r]);
        }
        float bias = b3[tid];
        #pragma unroll
        for (int r = 0; r < 8; ++r) sA[r][tid] = fmaxf(a[r] + bias, 0.f);
    }
    __syncthreads();
    {
        float a[8];
        #pragma unroll
        for (int r = 0; r < 8; ++r) a[r] = 0.f;
        for (int k = 0; k < WID; ++k) {
            float w = W4[k * WID + tid];
            #pragma unroll
            for (int r = 0; r < 8; ++r) a[r] = fmaf(sA[r][k], w, a[r]);
        }
        float bias = b4[tid];
        #pragma unroll
        for (int r = 0; r < 8; ++r) sB[r][tid] = fmaxf(a[r] + bias, 0.f);
    }
    __syncthreads();
    if (tid < 8) {
        float a = b5[0];
        for (int k = 0; k < WID; ++k) a = fmaf(sB[tid][k], W5[k], a);
        out_scores[r0 + tid] = 1.f / (1.f + __expf(-a));
    }
}

// ---------------------------------------------------------------- K5: cur[B,F,C] f32 -> out0[B,C,F] f32
__global__ void k_transpose_out(const float* __restrict__ cur, float* __restrict__ out) {
    __shared__ float tile[32][33];
    int b = blockIdx.z;
    int f0 = blockIdx.x * 32, c0 = blockIdx.y * 32;
    int tx = threadIdx.x, ty = threadIdx.y;
    #pragma unroll
    for (int i = 0; i < 4; ++i) {
        int f = f0 + ty + i * 8;
        tile[ty + i * 8][tx] = cur[((size_t)b * F + f) * C + c0 + tx];
    }
    __syncthreads();
    #pragma unroll
    for (int i = 0; i < 4; ++i) {
        int c = c0 + ty + i * 8;
        out[((size_t)b * C + c) * F + f0 + tx] = tile[tx][ty + i * 8];
    }
}

// ----------------------------------------------------------------
extern "C" void kernel_launch(void* const* d_in, const int* in_sizes, int n_in,
                              void* d_out, int out_size, void* d_ws, size_t ws_size,
                              hipStream_t stream) {
    const int* levels = (const int*)d_in[15];
    int Bd = in_sizes[15] / NLV;                  // ring capacity per level

    const size_t n = (size_t)NB * F * C;          // 589824
    float* cur  = (float*)d_ws;
    float* qh   = cur + n;
    float* khT  = qh + n;
    float* vhT  = khT + n;
    float* khT0 = vhT + n;                        // khT0/vhT0 contiguous after khT/vhT
    float* vhT0 = khT0 + n;
    float* wbuf = vhT0 + n;                       // fp32 weight copies, 296193 floats
    int*   permIdx = (int*)(wbuf + 296193 + 3);
    int*   flag = permIdx + F;
    int*   bar  = flag + 1;                       // bar[0]=cnt, bar[1]=gen

    const int oWq = 0,       oWk = 16384,  oWv = 32768,  oWo = 49152;
    const int oW1 = 65536,   oB1 = 98304;
    const int oW2 = 98560,   oB2 = 164096;
    const int oW3 = 164352,  oB3 = 229888;
    const int oW4 = 230144,  oB4 = 295680;
    const int oW5 = 295936,  oB5 = 296192;
    const int wtot = 296193;

    WSegs segs = {{
        { d_in[1],  oWq, 16384 }, { d_in[2],  oWk, 16384 },
        { d_in[3],  oWv, 16384 }, { d_in[4],  oWo, 16384 },
        { d_in[5],  oW1, 32768 }, { d_in[6],  oB1, 256 },
        { d_in[7],  oW2, 65536 }, { d_in[8],  oB2, 256 },
        { d_in[9],  oW3, 65536 }, { d_in[10], oB3, 256 },
        { d_in[11], oW4, 65536 }, { d_in[12], oB4, 256 },
        { d_in[13], oW5, 256 },   { d_in[14], oB5, 1 },
    }};

    // host-side ring prefix (pure function of GRIDN; matches k_perm's device result)
    Rings rings;
    int gmax = 2;
    {
        int cnt[NLV];
        for (int l = 0; l < NLV; ++l) cnt[l] = 0;
        for (int i = 0; i < GRIDN; ++i)
            for (int j = 0; j < GRIDN; ++j)
                cnt[(i < 24 ? 24 - i : i - 24) + (j < 24 ? 24 - j : j - 24)]++;
        rings.v[0] = 0;
        for (int l = 0; l < NLV; ++l) {
            rings.v[l + 1] = rings.v[l] + cnt[l];
            int nspair = (cnt[l] + 1) / 2;
            if (2 * nspair > gmax) gmax = 2 * nspair;
        }
    }

    float* out0 = (float*)d_out;                  // final.transpose(0,2,1): [B,C,F] fp32
    float* out1 = out0 + (size_t)NB * C * F;      // scores: [B,F,1] fp32

    k_detect<<<1, 256, 0, stream>>>(d_in[0], flag);
    k_perm<<<1, 256, 0, stream>>>(permIdx, bar);
    k_convert<<<(wtot + 255) / 256, 256, 0, stream>>>(segs, flag, wbuf, wtot);
    k_transpose_in<<<dim3(F / 32, C / 32, NB), dim3(32, 8), 0, stream>>>(d_in[0], flag, cur);
    k_proj_init<<<(NB * F) / 8, 128, 0, stream>>>(cur, permIdx, wbuf + oWq, wbuf + oWk, wbuf + oWv,
                                                  qh, khT, vhT);
    k_copy<<<(int)(2 * n / 4 + 255) / 256, 256, 0, stream>>>((const float4*)khT, (float4*)khT0,
                                                             (int)(2 * n / 4));

    // one plain-launch kernel with a manual grid barrier replaces 49 sequential launches;
    // gmax (<= ~96) blocks of 4 waves on 256 CUs are structurally co-resident.
    k_flood<<<gmax, 256, 0, stream>>>(Bd, gmax, rings, levels, permIdx, qh, cur,
                                      khT, vhT, khT0, vhT0,
                                      wbuf + oWk, wbuf + oWv, wbuf + oWo, bar);

    k_mlp<<<(NB * F) / 8, 256, 0, stream>>>(cur, wbuf + oW1, wbuf + oB1, wbuf + oW2, wbuf + oB2,
                                            wbuf + oW3, wbuf + oB3, wbuf + oW4, wbuf + oB4,
                                            wbuf + oW5, wbuf + oB5, out1);
    k_transpose_out<<<dim3(F / 32, C / 32, NB), dim3(32, 8), 0, stream>>>(cur, out0);
}

// Round 3
// 1839.940 us; speedup vs baseline: 2.4508x; 2.4508x over previous
//
#include <hip/hip_runtime.h>
#include <hip/hip_bf16.h>
#include <stdint.h>

#define GRIDN 48
#define F 2304
#define C 128
#define H 8
#define DH 16
#define NB 2          // batch (meshes)
#define WID 256
#define NLV 49        // BFS levels for GRID=48, anchor at (24,24)
#define SMH (H * 18)  // per-face static-softmax state: 8 heads x {m, l, acc[16]}

typedef __hip_bfloat16 bf16;

__device__ __forceinline__ float b2f(bf16 v) { return __bfloat162float(v); }

// ---------------------------------------------------------------- K-1: input dtype detector
__global__ void k_detect(const void* __restrict__ x, int* __restrict__ flag) {
    __shared__ int bad;
    if (threadIdx.x == 0) bad = 0;
    __syncthreads();
    const bf16* xb = (const bf16*)x;
    int insane = 0;
    #pragma unroll
    for (int i = 0; i < 8; ++i) {
        float v = b2f(xb[threadIdx.x * 8 + i]);
        if (!(fabsf(v) < 1e10f)) insane = 1;   // catches NaN/Inf/huge
    }
    if (insane) atomicOr(&bad, 1);
    __syncthreads();
    if (threadIdx.x == 0) *flag = bad;
}

// ---------------------------------------------------------------- K0: BFS-ring permutation of the key axis
__global__ void k_perm(int* __restrict__ permIdx) {
    __shared__ int cnt[NLV], start[NLV];
    int t = threadIdx.x;
    if (t < NLV) cnt[t] = 0;
    __syncthreads();
    for (int f = t; f < F; f += 256) {
        int d = abs(f / GRIDN - GRIDN / 2) + abs(f % GRIDN - GRIDN / 2);
        atomicAdd(&cnt[d], 1);
    }
    __syncthreads();
    if (t == 0) {
        int s = 0;
        for (int l = 0; l < NLV; ++l) { start[l] = s; s += cnt[l]; }
    }
    __syncthreads();
    for (int f = t; f < F; f += 256) {
        int d = abs(f / GRIDN - GRIDN / 2) + abs(f % GRIDN - GRIDN / 2);
        permIdx[f] = atomicAdd(&start[d], 1);
    }
}

// ---------------------------------------------------------------- K0b: convert all weights/biases to fp32
struct WSeg { const void* src; int off; int cnt; };
struct WSegs { WSeg s[14]; };

__global__ void k_convert(WSegs segs, const int* __restrict__ flag,
                          float* __restrict__ dst, int total) {
    int i = blockIdx.x * blockDim.x + threadIdx.x;
    if (i >= total) return;
    bool f32 = (*flag != 0);
    #pragma unroll 1
    for (int j = 0; j < 14; ++j) {
        int off = segs.s[j].off, cnt = segs.s[j].cnt;
        if (i >= off && i < off + cnt) {
            int k = i - off;
            dst[i] = f32 ? ((const float*)segs.s[j].src)[k]
                         : b2f(((const bf16*)segs.s[j].src)[k]);
            return;
        }
    }
}

// ---------------------------------------------------------------- K1: x[B,C,F] -> cur[B,F,C] f32
__global__ void k_transpose_in(const void* __restrict__ x, const int* __restrict__ flag,
                               float* __restrict__ cur) {
    __shared__ float tile[32][33];
    bool f32 = (*flag != 0);
    int b = blockIdx.z;
    int f0 = blockIdx.x * 32, c0 = blockIdx.y * 32;
    int tx = threadIdx.x, ty = threadIdx.y;            // 32 x 8
    #pragma unroll
    for (int i = 0; i < 4; ++i) {
        int c = c0 + ty + i * 8;
        size_t idx = ((size_t)b * C + c) * F + f0 + tx;
        tile[ty + i * 8][tx] = f32 ? ((const float*)x)[idx] : b2f(((const bf16*)x)[idx]);
    }
    __syncthreads();
    #pragma unroll
    for (int i = 0; i < 4; ++i) {
        int f = f0 + ty + i * 8;
        cur[((size_t)b * F + f) * C + c0 + tx] = tile[tx][ty + i * 8];
    }
}

// ---------------------------------------------------------------- K2: init projections.
__global__ __launch_bounds__(128) void k_proj_init(
        const float* __restrict__ cur, const int* __restrict__ permIdx,
        const float* __restrict__ Wq, const float* __restrict__ Wk, const float* __restrict__ Wv,
        float* __restrict__ qh, float* __restrict__ khT, float* __restrict__ vhT) {
    __shared__ float rows[8][C];
    int r0 = blockIdx.x * 8;
    int tid = threadIdx.x;  // 0..127 = output channel
    #pragma unroll
    for (int r = 0; r < 8; ++r) rows[r][tid] = cur[(size_t)(r0 + r) * C + tid];
    __syncthreads();
    float aq[8], ak[8], av[8];
    #pragma unroll
    for (int r = 0; r < 8; ++r) { aq[r] = 0.f; ak[r] = 0.f; av[r] = 0.f; }
    for (int k = 0; k < C; ++k) {
        float wq = Wq[k * C + tid];
        float wk = Wk[k * C + tid];
        float wv = Wv[k * C + tid];
        #pragma unroll
        for (int r = 0; r < 8; ++r) {
            float xv = rows[r][k];
            aq[r] = fmaf(xv, wq, aq[r]);
            ak[r] = fmaf(xv, wk, ak[r]);
            av[r] = fmaf(xv, wv, av[r]);
        }
    }
    const float scale = 0.25f;  // 1/sqrt(DH)
    #pragma unroll
    for (int r = 0; r < 8; ++r) {
        int grow = r0 + r;
        int mesh = grow / F, face = grow % F;
        int p = permIdx[face];
        qh[(size_t)grow * C + tid] = aq[r] * scale;
        khT[((size_t)mesh * C + tid) * F + p] = ak[r];
        vhT[((size_t)mesh * C + tid) * F + p] = av[r];
    }
}

struct Rings { int v[NLV + 1]; };
struct Pairs { int v[NLV + 1]; };

// ---------------------------------------------------------------- K2c: static attention partials.
// Runs right after k_proj_init, BEFORE any level updates khT/vhT — so khT/vhT still hold init
// values everywhere. For every query (all levels at once, fully parallel), compute the
// online-softmax partial state over key columns [rs, F) (the not-yet-updated region).
// Exactly reproduces the old kernel's khT0-shielded reads for [rs, F).
__global__ __launch_bounds__(256) void k_static(
        int Bd, Rings rings, Pairs pairs,
        const int* __restrict__ levels,
        const float* __restrict__ qh_all,
        const float* __restrict__ khT, const float* __restrict__ vhT,
        float* __restrict__ smS) {
    int bx = blockIdx.x;
    int mesh = bx & 1;                 // parity swizzle: mesh per XCD-parity (L2 locality)
    int gp = bx >> 1;                  // global pair id across all levels
    int lv = 0;
    while (gp >= pairs.v[lv + 1]) ++lv;
    int spair = gp - pairs.v[lv];
    int rs = rings.v[lv];
    int s0 = spair * 2, s1 = s0 + 1;
    int face0 = (s0 < Bd) ? levels[lv * Bd + s0] : F;
    int face1 = (s1 < Bd) ? levels[lv * Bd + s1] : F;
    bool a0 = (face0 >= 0 && face0 < F), a1 = (face1 >= 0 && face1 < F);
    if (!a0 && !a1) return;

    __shared__ float sQh[2][C];
    int tid = threadIdx.x;
    size_t row0 = ((size_t)mesh * F + face0) * C;
    size_t row1 = ((size_t)mesh * F + face1) * C;
    if (tid < C) sQh[0][tid] = a0 ? qh_all[row0 + tid] : 0.f;
    else { int c = tid - C; sQh[1][c] = a1 ? qh_all[row1 + c] : 0.f; }
    __syncthreads();

    int head = tid >> 5, sub = tid & 31;
    float q0[DH], q1[DH];
    #pragma unroll
    for (int d = 0; d < DH; ++d) { q0[d] = sQh[0][head * DH + d]; q1[d] = sQh[1][head * DH + d]; }

    const float* Kb = khT + ((size_t)mesh * C + head * DH) * F;
    const float* Vb = vhT + ((size_t)mesh * C + head * DH) * F;

    float m0 = -1e30f, l0 = 0.f, m1 = -1e30f, l1 = 0.f;
    float acc0[DH], acc1[DH];
    #pragma unroll
    for (int d = 0; d < DH; ++d) { acc0[d] = 0.f; acc1[d] = 0.f; }

    int base0 = rs & ~127;             // first tile may straddle rs: gate cols < rs to weight 0
    for (int base = base0; base < F; base += 128) {
        int p4 = base + 4 * sub;
        float sx0 = 0, sy0 = 0, sz0 = 0, sw0 = 0;
        float sx1 = 0, sy1 = 0, sz1 = 0, sw1 = 0;
        #pragma unroll
        for (int d = 0; d < DH; ++d) {
            float4 kk = *(const float4*)(Kb + d * F + p4);
            float a = q0[d], b = q1[d];
            sx0 = fmaf(a, kk.x, sx0); sy0 = fmaf(a, kk.y, sy0);
            sz0 = fmaf(a, kk.z, sz0); sw0 = fmaf(a, kk.w, sw0);
            sx1 = fmaf(b, kk.x, sx1); sy1 = fmaf(b, kk.y, sy1);
            sz1 = fmaf(b, kk.z, sz1); sw1 = fmaf(b, kk.w, sw1);
        }
        float g0 = 1.f, g1 = 1.f, g2 = 1.f, g3 = 1.f;
        if (base < rs) {               // block-uniform branch (leading edge tile)
            g0 = (p4     >= rs) ? 1.f : 0.f; g1 = (p4 + 1 >= rs) ? 1.f : 0.f;
            g2 = (p4 + 2 >= rs) ? 1.f : 0.f; g3 = (p4 + 3 >= rs) ? 1.f : 0.f;
        }
        float mx0 = fmaxf(fmaxf(sx0, sy0), fmaxf(sz0, sw0));
        float mn0 = fmaxf(m0, mx0);
        float c0 = __expf(m0 - mn0);
        float px0 = __expf(sx0 - mn0) * g0, py0 = __expf(sy0 - mn0) * g1;
        float pz0 = __expf(sz0 - mn0) * g2, pw0 = __expf(sw0 - mn0) * g3;
        l0 = fmaf(l0, c0, px0 + py0 + pz0 + pw0);
        m0 = mn0;
        float mx1 = fmaxf(fmaxf(sx1, sy1), fmaxf(sz1, sw1));
        float mn1 = fmaxf(m1, mx1);
        float c1e = __expf(m1 - mn1);
        float px1 = __expf(sx1 - mn1) * g0, py1 = __expf(sy1 - mn1) * g1;
        float pz1 = __expf(sz1 - mn1) * g2, pw1 = __expf(sw1 - mn1) * g3;
        l1 = fmaf(l1, c1e, px1 + py1 + pz1 + pw1);
        m1 = mn1;
        #pragma unroll
        for (int d = 0; d < DH; ++d) {
            float4 vv = *(const float4*)(Vb + d * F + p4);
            float w0 = fmaf(px0, vv.x, fmaf(py0, vv.y, fmaf(pz0, vv.z, pw0 * vv.w)));
            float w1 = fmaf(px1, vv.x, fmaf(py1, vv.y, fmaf(pz1, vv.z, pw1 * vv.w)));
            acc0[d] = fmaf(acc0[d], c0, w0);
            acc1[d] = fmaf(acc1[d], c1e, w1);
        }
    }

    // merge 32 per-lane states per head
    #pragma unroll
    for (int w = 16; w >= 1; w >>= 1) {
        float mo = __shfl_xor(m0, w), lo = __shfl_xor(l0, w);
        float mn = fmaxf(m0, mo);
        float ca = __expf(m0 - mn), cb = __expf(mo - mn);
        l0 = l0 * ca + lo * cb;
        #pragma unroll
        for (int d = 0; d < DH; ++d) {
            float ao = __shfl_xor(acc0[d], w);
            acc0[d] = acc0[d] * ca + ao * cb;
        }
        m0 = mn;
        mo = __shfl_xor(m1, w); lo = __shfl_xor(l1, w);
        mn = fmaxf(m1, mo);
        ca = __expf(m1 - mn); cb = __expf(mo - mn);
        l1 = l1 * ca + lo * cb;
        #pragma unroll
        for (int d = 0; d < DH; ++d) {
            float ao = __shfl_xor(acc1[d], w);
            acc1[d] = acc1[d] * ca + ao * cb;
        }
        m1 = mn;
    }
    if (sub == 0) {
        if (a0) {
            float* S = smS + (size_t)(mesh * F + face0) * SMH + head * 18;
            S[0] = m0; S[1] = l0;
            #pragma unroll
            for (int d = 0; d < DH; ++d) S[2 + d] = acc0[d];
        }
        if (a1) {
            float* S = smS + (size_t)(mesh * F + face1) * SMH + head * 18;
            S[0] = m1; S[1] = l1;
            #pragma unroll
            for (int d = 0; d < DH; ++d) S[2 + d] = acc1[d];
        }
    }
}

// ---------------------------------------------------------------- K3: one BFS level, dynamic part only.
// Streams only the updated prefix [0, rs) of khT/vhT (columns written by earlier levels; stable
// during this level — same-level refresh writes go to [rs, re), never read here). Tail tile
// straddling rs gates cols >= rs to weight 0. Merges with the precomputed static state.
__global__ __launch_bounds__(256) void k_level(
        int lv, int Bd, int rs,
        const int* __restrict__ levels, const int* __restrict__ permIdx,
        const float* __restrict__ qh_all, float* __restrict__ cur,
        float* __restrict__ khT, float* __restrict__ vhT,
        const float* __restrict__ smS,
        const float* __restrict__ Wk, const float* __restrict__ Wv,
        const float* __restrict__ Wo) {
    int bx = blockIdx.x;
    int mesh = bx & 1;                 // parity swizzle: mesh per XCD-parity
    int spair = bx >> 1;
    int s0 = spair * 2, s1 = s0 + 1;
    int face0 = (s0 < Bd) ? levels[lv * Bd + s0] : F;
    int face1 = (s1 < Bd) ? levels[lv * Bd + s1] : F;
    bool a0 = (face0 >= 0 && face0 < F), a1 = (face1 >= 0 && face1 < F);
    if (!a0 && !a1) return;

    __shared__ float sQh[2][C], sQ[2][C], sRed[2][C], sNew[C];
    __shared__ float sL[2][H];
    int tid = threadIdx.x;
    size_t row0 = ((size_t)mesh * F + face0) * C;
    size_t row1 = ((size_t)mesh * F + face1) * C;
    if (tid < C) {
        if (a0) { sQ[0][tid] = cur[row0 + tid]; sQh[0][tid] = qh_all[row0 + tid]; }
        else    { sQ[0][tid] = 0.f; sQh[0][tid] = 0.f; }
    } else {
        int c = tid - C;
        if (a1) { sQ[1][c] = cur[row1 + c]; sQh[1][c] = qh_all[row1 + c]; }
        else    { sQ[1][c] = 0.f; sQh[1][c] = 0.f; }
    }
    __syncthreads();

    int head = tid >> 5, sub = tid & 31;
    float q0[DH], q1[DH];
    #pragma unroll
    for (int d = 0; d < DH; ++d) { q0[d] = sQh[0][head * DH + d]; q1[d] = sQh[1][head * DH + d]; }

    const float* Kb = khT + ((size_t)mesh * C + head * DH) * F;
    const float* Vb = vhT + ((size_t)mesh * C + head * DH) * F;

    float m0 = -1e30f, l0 = 0.f, m1 = -1e30f, l1 = 0.f;
    float acc0[DH], acc1[DH];
    #pragma unroll
    for (int d = 0; d < DH; ++d) { acc0[d] = 0.f; acc1[d] = 0.f; }

    for (int base = 0; base < rs; base += 128) {
        int p4 = base + 4 * sub;
        float sx0 = 0, sy0 = 0, sz0 = 0, sw0 = 0;
        float sx1 = 0, sy1 = 0, sz1 = 0, sw1 = 0;
        #pragma unroll
        for (int d = 0; d < DH; ++d) {
            float4 kk = *(const float4*)(Kb + d * F + p4);
            float a = q0[d], b = q1[d];
            sx0 = fmaf(a, kk.x, sx0); sy0 = fmaf(a, kk.y, sy0);
            sz0 = fmaf(a, kk.z, sz0); sw0 = fmaf(a, kk.w, sw0);
            sx1 = fmaf(b, kk.x, sx1); sy1 = fmaf(b, kk.y, sy1);
            sz1 = fmaf(b, kk.z, sz1); sw1 = fmaf(b, kk.w, sw1);
        }
        float g0 = 1.f, g1 = 1.f, g2 = 1.f, g3 = 1.f;
        if (base + 128 > rs) {         // block-uniform branch (tail tile)
            g0 = (p4     < rs) ? 1.f : 0.f; g1 = (p4 + 1 < rs) ? 1.f : 0.f;
            g2 = (p4 + 2 < rs) ? 1.f : 0.f; g3 = (p4 + 3 < rs) ? 1.f : 0.f;
        }
        float mx0 = fmaxf(fmaxf(sx0, sy0), fmaxf(sz0, sw0));
        float mn0 = fmaxf(m0, mx0);
        float c0 = __expf(m0 - mn0);
        float px0 = __expf(sx0 - mn0) * g0, py0 = __expf(sy0 - mn0) * g1;
        float pz0 = __expf(sz0 - mn0) * g2, pw0 = __expf(sw0 - mn0) * g3;
        l0 = fmaf(l0, c0, px0 + py0 + pz0 + pw0);
        m0 = mn0;
        float mx1 = fmaxf(fmaxf(sx1, sy1), fmaxf(sz1, sw1));
        float mn1 = fmaxf(m1, mx1);
        float c1e = __expf(m1 - mn1);
        float px1 = __expf(sx1 - mn1) * g0, py1 = __expf(sy1 - mn1) * g1;
        float pz1 = __expf(sz1 - mn1) * g2, pw1 = __expf(sw1 - mn1) * g3;
        l1 = fmaf(l1, c1e, px1 + py1 + pz1 + pw1);
        m1 = mn1;
        #pragma unroll
        for (int d = 0; d < DH; ++d) {
            float4 vv = *(const float4*)(Vb + d * F + p4);
            float w0 = fmaf(px0, vv.x, fmaf(py0, vv.y, fmaf(pz0, vv.z, pw0 * vv.w)));
            float w1 = fmaf(px1, vv.x, fmaf(py1, vv.y, fmaf(pz1, vv.z, pw1 * vv.w)));
            acc0[d] = fmaf(acc0[d], c0, w0);
            acc1[d] = fmaf(acc1[d], c1e, w1);
        }
    }

    // merge 32 per-lane online-softmax states per head
    #pragma unroll
    for (int w = 16; w >= 1; w >>= 1) {
        float mo = __shfl_xor(m0, w), lo = __shfl_xor(l0, w);
        float mn = fmaxf(m0, mo);
        float ca = __expf(m0 - mn), cb = __expf(mo - mn);
        l0 = l0 * ca + lo * cb;
        #pragma unroll
        for (int d = 0; d < DH; ++d) {
            float ao = __shfl_xor(acc0[d], w);
            acc0[d] = acc0[d] * ca + ao * cb;
        }
        m0 = mn;
        mo = __shfl_xor(m1, w); lo = __shfl_xor(l1, w);
        mn = fmaxf(m1, mo);
        ca = __expf(m1 - mn); cb = __expf(mo - mn);
        l1 = l1 * ca + lo * cb;
        #pragma unroll
        for (int d = 0; d < DH; ++d) {
            float ao = __shfl_xor(acc1[d], w);
            acc1[d] = acc1[d] * ca + ao * cb;
        }
        m1 = mn;
    }
    if (sub == 0) {
        // merge dynamic state with the precomputed static state over [rs, F)
        {
            int fr = a0 ? face0 : 0;   // clamp for pad query; result discarded
            const float* S = smS + (size_t)(mesh * F + fr) * SMH + head * 18;
            float ms = S[0], ls = S[1];
            float mn = fmaxf(m0, ms);
            float ca = __expf(m0 - mn), cb = __expf(ms - mn);
            sL[0][head] = l0 * ca + ls * cb;
            #pragma unroll
            for (int d = 0; d < DH; ++d)
                sRed[0][head * DH + d] = fmaf(acc0[d], ca, S[2 + d] * cb);
        }
        {
            int fr = a1 ? face1 : 0;
            const float* S = smS + (size_t)(mesh * F + fr) * SMH + head * 18;
            float ms = S[0], ls = S[1];
            float mn = fmaxf(m1, ms);
            float ca = __expf(m1 - mn), cb = __expf(ms - mn);
            sL[1][head] = l1 * ca + ls * cb;
            #pragma unroll
            for (int d = 0; d < DH; ++d)
                sRed[1][head * DH + d] = fmaf(acc1[d], ca, S[2 + d] * cb);
        }
    }
    __syncthreads();
    if (tid < C) sRed[0][tid] = sRed[0][tid] / sL[0][tid >> 4];
    else { int c = tid - C; sRed[1][c] = sRed[1][c] / sL[1][c >> 4]; }
    __syncthreads();

    // epilogue per query: out-proj + resid, then K/V column refresh (ring-lv cols [rs,re);
    // nobody reads those columns during this level, so the eager write is race-free)
    #pragma unroll 1
    for (int j = 0; j < 2; ++j) {
        bool act = j == 0 ? a0 : a1;
        if (!act) continue;
        size_t rowj = j == 0 ? row0 : row1;
        int facej = j == 0 ? face0 : face1;
        if (tid < C) {
            float o = 0.f;
            for (int k = 0; k < C; ++k) o = fmaf(sRed[j][k], Wo[k * C + tid], o);
            float nv = sQ[j][tid] + o;
            sNew[tid] = nv;
            cur[rowj + tid] = nv;
        }
        __syncthreads();
        int p = permIdx[facej];
        if (tid < C) {
            float a = 0.f;
            for (int k = 0; k < C; ++k) a = fmaf(sNew[k], Wk[k * C + tid], a);
            khT[((size_t)mesh * C + tid) * F + p] = a;
        } else {
            int c = tid - C;
            float a = 0.f;
            for (int k = 0; k < C; ++k) a = fmaf(sNew[k], Wv[k * C + c], a);
            vhT[((size_t)mesh * C + c) * F + p] = a;
        }
        __syncthreads();
    }
}

// ---------------------------------------------------------------- K4: 5-layer MLP + sigmoid (8 rows/block)
__global__ __launch_bounds__(256) void k_mlp(
        const float* __restrict__ cur,
        const float* __restrict__ W1, const float* __restrict__ b1,
        const float* __restrict__ W2, const float* __restrict__ b2,
        const float* __restrict__ W3, const float* __restrict__ b3,
        const float* __restrict__ W4, const float* __restrict__ b4,
        const float* __restrict__ W5, const float* __restrict__ b5,
        float* __restrict__ out_scores) {
    __shared__ float sIn[8][C];
    __shared__ float sA[8][WID];
    __shared__ float sB[8][WID];
    int tid = threadIdx.x;                        // 0..255
    int r0 = blockIdx.x * 8;
    for (int i = tid; i < 8 * C; i += 256) sIn[i >> 7][i & 127] = cur[(size_t)r0 * C + i];
    __syncthreads();
    {
        float a[8];
        #pragma unroll
        for (int r = 0; r < 8; ++r) a[r] = 0.f;
        for (int k = 0; k < C; ++k) {
            float w = W1[k * WID + tid];
            #pragma unroll
            for (int r = 0; r < 8; ++r) a[r] = fmaf(sIn[r][k], w, a[r]);
        }
        float bias = b1[tid];
        #pragma unroll
        for (int r = 0; r < 8; ++r) sA[r][tid] = fmaxf(a[r] + bias, 0.f);
    }
    __syncthreads();
    {
        float a[8];
        #pragma unroll
        for (int r = 0; r < 8; ++r) a[r] = 0.f;
        for (int k = 0; k < WID; ++k) {
            float w = W2[k * WID + tid];
            #pragma unroll
            for (int r = 0; r < 8; ++r) a[r] = fmaf(sA[r][k], w, a[r]);
        }
        float bias = b2[tid];
        #pragma unroll
        for (int r = 0; r < 8; ++r) sB[r][tid] = fmaxf(a[r] + bias, 0.f);
    }
    __syncthreads();
    {
        float a[8];
        #pragma unroll
        for (int r = 0; r < 8; ++r) a[r] = 0.f;
        for (int k = 0; k < WID; ++k) {
            float w = W3[k * WID + tid];
            #pragma unroll
            for (int r = 0; r < 8; ++r) a[r] = fmaf(sB[r][k], w, a[r]);
        }
        float bias = b3[tid];
        #pragma unroll
        for (int r = 0; r < 8; ++r) sA[r][tid] = fmaxf(a[r] + bias, 0.f);
    }
    __syncthreads();
    {
        float a[8];
        #pragma unroll
        for (int r = 0; r < 8; ++r) a[r] = 0.f;
        for (int k = 0; k < WID; ++k) {
            float w = W4[k * WID + tid];
            #pragma unroll
            for (int r = 0; r < 8; ++r) a[r] = fmaf(sA[r][k], w, a[r]);
        }
        float bias = b4[tid];
        #pragma unroll
        for (int r = 0; r < 8; ++r) sB[r][tid] = fmaxf(a[r] + bias, 0.f);
    }
    __syncthreads();
    if (tid < 8) {
        float a = b5[0];
        for (int k = 0; k < WID; ++k) a = fmaf(sB[tid][k], W5[k], a);
        out_scores[r0 + tid] = 1.f / (1.f + __expf(-a));
    }
}

// ---------------------------------------------------------------- K5: cur[B,F,C] f32 -> out0[B,C,F] f32
__global__ void k_transpose_out(const float* __restrict__ cur, float* __restrict__ out) {
    __shared__ float tile[32][33];
    int b = blockIdx.z;
    int f0 = blockIdx.x * 32, c0 = blockIdx.y * 32;
    int tx = threadIdx.x, ty = threadIdx.y;
    #pragma unroll
    for (int i = 0; i < 4; ++i) {
        int f = f0 + ty + i * 8;
        tile[ty + i * 8][tx] = cur[((size_t)b * F + f) * C + c0 + tx];
    }
    __syncthreads();
    #pragma unroll
    for (int i = 0; i < 4; ++i) {
        int c = c0 + ty + i * 8;
        out[((size_t)b * C + c) * F + f0 + tx] = tile[tx][ty + i * 8];
    }
}

// ----------------------------------------------------------------
extern "C" void kernel_launch(void* const* d_in, const int* in_sizes, int n_in,
                              void* d_out, int out_size, void* d_ws, size_t ws_size,
                              hipStream_t stream) {
    const int* levels = (const int*)d_in[15];
    int Bd = in_sizes[15] / NLV;                  // ring capacity per level

    const size_t n = (size_t)NB * F * C;          // 589824
    float* cur  = (float*)d_ws;
    float* qh   = cur + n;
    float* khT  = qh + n;
    float* vhT  = khT + n;
    float* wbuf = vhT + n;                        // fp32 weight copies, 296193 floats
    int*   permIdx = (int*)(wbuf + 296193 + 3);
    int*   flag = permIdx + F;
    float* smS  = (float*)(flag + 3);             // static softmax state: (NB*F)*SMH floats

    const int oWq = 0,       oWk = 16384,  oWv = 32768,  oWo = 49152;
    const int oW1 = 65536,   oB1 = 98304;
    const int oW2 = 98560,   oB2 = 164096;
    const int oW3 = 164352,  oB3 = 229888;
    const int oW4 = 230144,  oB4 = 295680;
    const int oW5 = 295936,  oB5 = 296192;
    const int wtot = 296193;

    WSegs segs = {{
        { d_in[1],  oWq, 16384 }, { d_in[2],  oWk, 16384 },
        { d_in[3],  oWv, 16384 }, { d_in[4],  oWo, 16384 },
        { d_in[5],  oW1, 32768 }, { d_in[6],  oB1, 256 },
        { d_in[7],  oW2, 65536 }, { d_in[8],  oB2, 256 },
        { d_in[9],  oW3, 65536 }, { d_in[10], oB3, 256 },
        { d_in[11], oW4, 65536 }, { d_in[12], oB4, 256 },
        { d_in[13], oW5, 256 },   { d_in[14], oB5, 1 },
    }};

    // host-side ring prefix + pair prefix (pure function of GRIDN; matches k_perm)
    Rings rings;
    Pairs pairs;
    int totPairs = 0;
    {
        int cnt[NLV];
        for (int l = 0; l < NLV; ++l) cnt[l] = 0;
        for (int i = 0; i < GRIDN; ++i)
            for (int j = 0; j < GRIDN; ++j)
                cnt[(i < 24 ? 24 - i : i - 24) + (j < 24 ? 24 - j : j - 24)]++;
        rings.v[0] = 0;
        pairs.v[0] = 0;
        for (int l = 0; l < NLV; ++l) {
            rings.v[l + 1] = rings.v[l] + cnt[l];
            pairs.v[l + 1] = pairs.v[l] + (cnt[l] + 1) / 2;
        }
        totPairs = pairs.v[NLV];
    }

    float* out0 = (float*)d_out;                  // final.transpose(0,2,1): [B,C,F] fp32
    float* out1 = out0 + (size_t)NB * C * F;      // scores: [B,F,1] fp32

    k_detect<<<1, 256, 0, stream>>>(d_in[0], flag);
    k_perm<<<1, 256, 0, stream>>>(permIdx);
    k_convert<<<(wtot + 255) / 256, 256, 0, stream>>>(segs, flag, wbuf, wtot);
    k_transpose_in<<<dim3(F / 32, C / 32, NB), dim3(32, 8), 0, stream>>>(d_in[0], flag, cur);
    k_proj_init<<<(NB * F) / 8, 128, 0, stream>>>(cur, permIdx, wbuf + oWq, wbuf + oWk, wbuf + oWv,
                                                  qh, khT, vhT);

    // static partials for ALL queries at once (khT/vhT still pristine here)
    k_static<<<2 * totPairs, 256, 0, stream>>>(Bd, rings, pairs, levels, qh, khT, vhT, smS);

    for (int lv = 0; lv < NLV; ++lv) {
        int rs = rings.v[lv], re = rings.v[lv + 1];
        int ring = re - rs;
        int nspair = (ring + 1) / 2;
        k_level<<<2 * nspair, 256, 0, stream>>>(lv, Bd, rs, levels, permIdx, qh, cur,
                                                khT, vhT, smS,
                                                wbuf + oWk, wbuf + oWv, wbuf + oWo);
    }

    k_mlp<<<(NB * F) / 8, 256, 0, stream>>>(cur, wbuf + oW1, wbuf + oB1, wbuf + oW2, wbuf + oB2,
                                            wbuf + oW3, wbuf + oB3, wbuf + oW4, wbuf + oB4,
                                            wbuf + oW5, wbuf + oB5, out1);
    k_transpose_out<<<dim3(F / 32, C / 32, NB), dim3(32, 8), 0, stream>>>(cur, out0);
}

// Round 4
// 1577.377 us; speedup vs baseline: 2.8587x; 1.1665x over previous
//
#include <hip/hip_runtime.h>
#include <hip/hip_bf16.h>
#include <stdint.h>

#define GRIDN 48
#define F 2304
#define C 128
#define H 8
#define DH 16
#define NB 2          // batch (meshes)
#define WID 256
#define NLV 49        // BFS levels for GRID=48, anchor at (24,24)
#define SMH (H * 18)  // per-face static-softmax state: 8 heads x {m, l, acc[16]}
#define GLV 7         // levels per k_group launch (49 = 7 x 7)

typedef __hip_bfloat16 bf16;

__device__ __forceinline__ float b2f(bf16 v) { return __bfloat162float(v); }

// ---------------------------------------------------------------- K0: dtype detect + BFS-ring perm + flag clear
__global__ void k_permdetect(const void* __restrict__ x, int* __restrict__ flag,
                             int* __restrict__ permIdx, int* __restrict__ lvflags) {
    __shared__ int cnt[NLV], start[NLV];
    __shared__ int bad;
    int t = threadIdx.x;
    if (t == 0) bad = 0;
    if (t < NLV) cnt[t] = 0;
    for (int i = t; i < 2 * NLV; i += 256) lvflags[i] = 0;
    __syncthreads();
    {   // dtype detect on first 2048 elements
        const bf16* xb = (const bf16*)x;
        int insane = 0;
        #pragma unroll
        for (int i = 0; i < 8; ++i) {
            float v = b2f(xb[t * 8 + i]);
            if (!(fabsf(v) < 1e10f)) insane = 1;
        }
        if (insane) atomicOr(&bad, 1);
    }
    for (int f = t; f < F; f += 256) {
        int d = abs(f / GRIDN - GRIDN / 2) + abs(f % GRIDN - GRIDN / 2);
        atomicAdd(&cnt[d], 1);
    }
    __syncthreads();
    if (t == 0) {
        int s = 0;
        for (int l = 0; l < NLV; ++l) { start[l] = s; s += cnt[l]; }
        *flag = bad;
    }
    __syncthreads();
    for (int f = t; f < F; f += 256) {
        int d = abs(f / GRIDN - GRIDN / 2) + abs(f % GRIDN - GRIDN / 2);
        permIdx[f] = atomicAdd(&start[d], 1);
    }
}

// ---------------------------------------------------------------- K0b: convert all weights/biases to fp32
struct WSeg { const void* src; int off; int cnt; };
struct WSegs { WSeg s[14]; };

__global__ void k_convert(WSegs segs, const int* __restrict__ flag,
                          float* __restrict__ dst, int total) {
    int i = blockIdx.x * blockDim.x + threadIdx.x;
    if (i >= total) return;
    bool f32 = (*flag != 0);
    #pragma unroll 1
    for (int j = 0; j < 14; ++j) {
        int off = segs.s[j].off, cnt = segs.s[j].cnt;
        if (i >= off && i < off + cnt) {
            int k = i - off;
            dst[i] = f32 ? ((const float*)segs.s[j].src)[k]
                         : b2f(((const bf16*)segs.s[j].src)[k]);
            return;
        }
    }
}

// ---------------------------------------------------------------- K1: x[B,C,F] -> cur[B,F,C] f32
__global__ void k_transpose_in(const void* __restrict__ x, const int* __restrict__ flag,
                               float* __restrict__ cur) {
    __shared__ float tile[32][33];
    bool f32 = (*flag != 0);
    int b = blockIdx.z;
    int f0 = blockIdx.x * 32, c0 = blockIdx.y * 32;
    int tx = threadIdx.x, ty = threadIdx.y;            // 32 x 8
    #pragma unroll
    for (int i = 0; i < 4; ++i) {
        int c = c0 + ty + i * 8;
        size_t idx = ((size_t)b * C + c) * F + f0 + tx;
        tile[ty + i * 8][tx] = f32 ? ((const float*)x)[idx] : b2f(((const bf16*)x)[idx]);
    }
    __syncthreads();
    #pragma unroll
    for (int i = 0; i < 4; ++i) {
        int f = f0 + ty + i * 8;
        cur[((size_t)b * F + f) * C + c0 + tx] = tile[tx][ty + i * 8];
    }
}

// ---------------------------------------------------------------- K2: init projections.
__global__ __launch_bounds__(128) void k_proj_init(
        const float* __restrict__ cur, const int* __restrict__ permIdx,
        const float* __restrict__ Wq, const float* __restrict__ Wk, const float* __restrict__ Wv,
        float* __restrict__ qh, float* __restrict__ khT, float* __restrict__ vhT) {
    __shared__ float rows[8][C];
    int r0 = blockIdx.x * 8;
    int tid = threadIdx.x;  // 0..127 = output channel
    #pragma unroll
    for (int r = 0; r < 8; ++r) rows[r][tid] = cur[(size_t)(r0 + r) * C + tid];
    __syncthreads();
    float aq[8], ak[8], av[8];
    #pragma unroll
    for (int r = 0; r < 8; ++r) { aq[r] = 0.f; ak[r] = 0.f; av[r] = 0.f; }
    for (int k = 0; k < C; ++k) {
        float wq = Wq[k * C + tid];
        float wk = Wk[k * C + tid];
        float wv = Wv[k * C + tid];
        #pragma unroll
        for (int r = 0; r < 8; ++r) {
            float xv = rows[r][k];
            aq[r] = fmaf(xv, wq, aq[r]);
            ak[r] = fmaf(xv, wk, ak[r]);
            av[r] = fmaf(xv, wv, av[r]);
        }
    }
    const float scale = 0.25f;  // 1/sqrt(DH)
    #pragma unroll
    for (int r = 0; r < 8; ++r) {
        int grow = r0 + r;
        int mesh = grow / F, face = grow % F;
        int p = permIdx[face];
        qh[(size_t)grow * C + tid] = aq[r] * scale;
        khT[((size_t)mesh * C + tid) * F + p] = ak[r];
        vhT[((size_t)mesh * C + tid) * F + p] = av[r];
    }
}

struct Rings { int v[NLV + 1]; };
struct Pairs { int v[NLV + 1]; };

// ---------------------------------------------------------------- K2c: static attention partials.
// (unchanged from round 3 — runs on pristine khT/vhT, covers key columns [rs_lv, F) per query)
__global__ __launch_bounds__(256) void k_static(
        int Bd, Rings rings, Pairs pairs,
        const int* __restrict__ levels,
        const float* __restrict__ qh_all,
        const float* __restrict__ khT, const float* __restrict__ vhT,
        float* __restrict__ smS) {
    int bx = blockIdx.x;
    int mesh = bx & 1;
    int gp = bx >> 1;
    int lv = 0;
    while (gp >= pairs.v[lv + 1]) ++lv;
    int spair = gp - pairs.v[lv];
    int rs = rings.v[lv];
    int s0 = spair * 2, s1 = s0 + 1;
    int face0 = (s0 < Bd) ? levels[lv * Bd + s0] : F;
    int face1 = (s1 < Bd) ? levels[lv * Bd + s1] : F;
    bool a0 = (face0 >= 0 && face0 < F), a1 = (face1 >= 0 && face1 < F);
    if (!a0 && !a1) return;

    __shared__ float sQh[2][C];
    int tid = threadIdx.x;
    size_t row0 = ((size_t)mesh * F + face0) * C;
    size_t row1 = ((size_t)mesh * F + face1) * C;
    if (tid < C) sQh[0][tid] = a0 ? qh_all[row0 + tid] : 0.f;
    else { int c = tid - C; sQh[1][c] = a1 ? qh_all[row1 + c] : 0.f; }
    __syncthreads();

    int head = tid >> 5, sub = tid & 31;
    float q0[DH], q1[DH];
    #pragma unroll
    for (int d = 0; d < DH; ++d) { q0[d] = sQh[0][head * DH + d]; q1[d] = sQh[1][head * DH + d]; }

    const float* Kb = khT + ((size_t)mesh * C + head * DH) * F;
    const float* Vb = vhT + ((size_t)mesh * C + head * DH) * F;

    float m0 = -1e30f, l0 = 0.f, m1 = -1e30f, l1 = 0.f;
    float acc0[DH], acc1[DH];
    #pragma unroll
    for (int d = 0; d < DH; ++d) { acc0[d] = 0.f; acc1[d] = 0.f; }

    int base0 = rs & ~127;
    for (int base = base0; base < F; base += 128) {
        int p4 = base + 4 * sub;
        float sx0 = 0, sy0 = 0, sz0 = 0, sw0 = 0;
        float sx1 = 0, sy1 = 0, sz1 = 0, sw1 = 0;
        #pragma unroll
        for (int d = 0; d < DH; ++d) {
            float4 kk = *(const float4*)(Kb + d * F + p4);
            float a = q0[d], b = q1[d];
            sx0 = fmaf(a, kk.x, sx0); sy0 = fmaf(a, kk.y, sy0);
            sz0 = fmaf(a, kk.z, sz0); sw0 = fmaf(a, kk.w, sw0);
            sx1 = fmaf(b, kk.x, sx1); sy1 = fmaf(b, kk.y, sy1);
            sz1 = fmaf(b, kk.z, sz1); sw1 = fmaf(b, kk.w, sw1);
        }
        float g0 = 1.f, g1 = 1.f, g2 = 1.f, g3 = 1.f;
        if (base < rs) {
            g0 = (p4     >= rs) ? 1.f : 0.f; g1 = (p4 + 1 >= rs) ? 1.f : 0.f;
            g2 = (p4 + 2 >= rs) ? 1.f : 0.f; g3 = (p4 + 3 >= rs) ? 1.f : 0.f;
        }
        float mx0 = fmaxf(fmaxf(sx0, sy0), fmaxf(sz0, sw0));
        float mn0 = fmaxf(m0, mx0);
        float c0 = __expf(m0 - mn0);
        float px0 = __expf(sx0 - mn0) * g0, py0 = __expf(sy0 - mn0) * g1;
        float pz0 = __expf(sz0 - mn0) * g2, pw0 = __expf(sw0 - mn0) * g3;
        l0 = fmaf(l0, c0, px0 + py0 + pz0 + pw0);
        m0 = mn0;
        float mx1 = fmaxf(fmaxf(sx1, sy1), fmaxf(sz1, sw1));
        float mn1 = fmaxf(m1, mx1);
        float c1e = __expf(m1 - mn1);
        float px1 = __expf(sx1 - mn1) * g0, py1 = __expf(sy1 - mn1) * g1;
        float pz1 = __expf(sz1 - mn1) * g2, pw1 = __expf(sw1 - mn1) * g3;
        l1 = fmaf(l1, c1e, px1 + py1 + pz1 + pw1);
        m1 = mn1;
        #pragma unroll
        for (int d = 0; d < DH; ++d) {
            float4 vv = *(const float4*)(Vb + d * F + p4);
            float w0 = fmaf(px0, vv.x, fmaf(py0, vv.y, fmaf(pz0, vv.z, pw0 * vv.w)));
            float w1 = fmaf(px1, vv.x, fmaf(py1, vv.y, fmaf(pz1, vv.z, pw1 * vv.w)));
            acc0[d] = fmaf(acc0[d], c0, w0);
            acc1[d] = fmaf(acc1[d], c1e, w1);
        }
    }

    #pragma unroll
    for (int w = 16; w >= 1; w >>= 1) {
        float mo = __shfl_xor(m0, w), lo = __shfl_xor(l0, w);
        float mn = fmaxf(m0, mo);
        float ca = __expf(m0 - mn), cb = __expf(mo - mn);
        l0 = l0 * ca + lo * cb;
        #pragma unroll
        for (int d = 0; d < DH; ++d) {
            float ao = __shfl_xor(acc0[d], w);
            acc0[d] = acc0[d] * ca + ao * cb;
        }
        m0 = mn;
        mo = __shfl_xor(m1, w); lo = __shfl_xor(l1, w);
        mn = fmaxf(m1, mo);
        ca = __expf(m1 - mn); cb = __expf(mo - mn);
        l1 = l1 * ca + lo * cb;
        #pragma unroll
        for (int d = 0; d < DH; ++d) {
            float ao = __shfl_xor(acc1[d], w);
            acc1[d] = acc1[d] * ca + ao * cb;
        }
        m1 = mn;
    }
    if (sub == 0) {
        if (a0) {
            float* S = smS + (size_t)(mesh * F + face0) * SMH + head * 18;
            S[0] = m0; S[1] = l0;
            #pragma unroll
            for (int d = 0; d < DH; ++d) S[2 + d] = acc0[d];
        }
        if (a1) {
            float* S = smS + (size_t)(mesh * F + face1) * SMH + head * 18;
            S[0] = m1; S[1] = l1;
            #pragma unroll
            for (int d = 0; d < DH; ++d) S[2 + d] = acc1[d];
        }
    }
}

// ---------------------------------------------------------------- K3: GLV BFS levels per launch.
// Sub-level g's blocks: main stream over [0, rs0) (prior-launch data, kernel-boundary coherent),
// then fold staged columns of sub-levels lv0..lv-1 (same-launch data, relaxed agent-scope atomic
// staging — per-access coherent at L3, no cache invalidation), then static merge + epilogue.
// Producers stage their updated K/V columns + release-add a per-(level,mesh) flag.
// Block order is monotone in sub-level; producers never wait -> no deadlock.
struct Grp { int lv0; int rs0; int bofs[GLV + 1]; int rs[GLV]; int re[GLV]; int ns[GLV]; };

__global__ __launch_bounds__(256, 3) void k_group(
        int Bd, Grp grp,
        const int* __restrict__ levels, const int* __restrict__ permIdx,
        const float* __restrict__ qh_all, float* __restrict__ cur,
        float* __restrict__ khT, float* __restrict__ vhT,
        const float* __restrict__ smS,
        const float* __restrict__ Wk, const float* __restrict__ Wv,
        const float* __restrict__ Wo,
        float* __restrict__ stgK, float* __restrict__ stgV,
        int* __restrict__ lvflags) {
    int bx = blockIdx.x;
    int g = 0;
    while (bx >= grp.bofs[g + 1]) ++g;            // sub-level (monotone in blockIdx)
    int lb = bx - grp.bofs[g];
    int mesh = lb & 1;
    int spair = lb >> 1;
    int lv = grp.lv0 + g;
    int rs0 = grp.rs0;

    int s0 = spair * 2, s1 = s0 + 1;
    int face0 = (s0 < Bd) ? levels[lv * Bd + s0] : F;
    int face1 = (s1 < Bd) ? levels[lv * Bd + s1] : F;
    bool a0 = (face0 >= 0 && face0 < F), a1 = (face1 >= 0 && face1 < F);

    __shared__ float sQh[2][C], sQ[2][C], sRed[2][C], sNew[C];
    __shared__ float sL[2][H];
    int tid = threadIdx.x;
    size_t row0 = ((size_t)mesh * F + face0) * C;
    size_t row1 = ((size_t)mesh * F + face1) * C;
    if (tid < C) {
        if (a0) { sQ[0][tid] = cur[row0 + tid]; sQh[0][tid] = qh_all[row0 + tid]; }
        else    { sQ[0][tid] = 0.f; sQh[0][tid] = 0.f; }
    } else {
        int c = tid - C;
        if (a1) { sQ[1][c] = cur[row1 + c]; sQh[1][c] = qh_all[row1 + c]; }
        else    { sQ[1][c] = 0.f; sQh[1][c] = 0.f; }
    }
    __syncthreads();

    int head = tid >> 5, sub = tid & 31;
    float q0[DH], q1[DH];
    #pragma unroll
    for (int d = 0; d < DH; ++d) { q0[d] = sQh[0][head * DH + d]; q1[d] = sQh[1][head * DH + d]; }

    const float* Kb = khT + ((size_t)mesh * C + head * DH) * F;
    const float* Vb = vhT + ((size_t)mesh * C + head * DH) * F;

    float m0 = -1e30f, l0 = 0.f, m1 = -1e30f, l1 = 0.f;
    float acc0[DH], acc1[DH];
    #pragma unroll
    for (int d = 0; d < DH; ++d) { acc0[d] = 0.f; acc1[d] = 0.f; }

    // ---- main stream: prior-launch columns [0, rs0)
    for (int base = 0; base < rs0; base += 128) {
        int p4 = base + 4 * sub;
        float sx0 = 0, sy0 = 0, sz0 = 0, sw0 = 0;
        float sx1 = 0, sy1 = 0, sz1 = 0, sw1 = 0;
        #pragma unroll
        for (int d = 0; d < DH; ++d) {
            float4 kk = *(const float4*)(Kb + d * F + p4);
            float a = q0[d], b = q1[d];
            sx0 = fmaf(a, kk.x, sx0); sy0 = fmaf(a, kk.y, sy0);
            sz0 = fmaf(a, kk.z, sz0); sw0 = fmaf(a, kk.w, sw0);
            sx1 = fmaf(b, kk.x, sx1); sy1 = fmaf(b, kk.y, sy1);
            sz1 = fmaf(b, kk.z, sz1); sw1 = fmaf(b, kk.w, sw1);
        }
        float g0 = 1.f, g1 = 1.f, g2 = 1.f, g3 = 1.f;
        if (base + 128 > rs0) {
            g0 = (p4     < rs0) ? 1.f : 0.f; g1 = (p4 + 1 < rs0) ? 1.f : 0.f;
            g2 = (p4 + 2 < rs0) ? 1.f : 0.f; g3 = (p4 + 3 < rs0) ? 1.f : 0.f;
        }
        float mx0 = fmaxf(fmaxf(sx0, sy0), fmaxf(sz0, sw0));
        float mn0 = fmaxf(m0, mx0);
        float c0 = __expf(m0 - mn0);
        float px0 = __expf(sx0 - mn0) * g0, py0 = __expf(sy0 - mn0) * g1;
        float pz0 = __expf(sz0 - mn0) * g2, pw0 = __expf(sw0 - mn0) * g3;
        l0 = fmaf(l0, c0, px0 + py0 + pz0 + pw0);
        m0 = mn0;
        float mx1 = fmaxf(fmaxf(sx1, sy1), fmaxf(sz1, sw1));
        float mn1 = fmaxf(m1, mx1);
        float c1e = __expf(m1 - mn1);
        float px1 = __expf(sx1 - mn1) * g0, py1 = __expf(sy1 - mn1) * g1;
        float pz1 = __expf(sz1 - mn1) * g2, pw1 = __expf(sw1 - mn1) * g3;
        l1 = fmaf(l1, c1e, px1 + py1 + pz1 + pw1);
        m1 = mn1;
        #pragma unroll
        for (int d = 0; d < DH; ++d) {
            float4 vv = *(const float4*)(Vb + d * F + p4);
            float w0 = fmaf(px0, vv.x, fmaf(py0, vv.y, fmaf(pz0, vv.z, pw0 * vv.w)));
            float w1 = fmaf(px1, vv.x, fmaf(py1, vv.y, fmaf(pz1, vv.z, pw1 * vv.w)));
            acc0[d] = fmaf(acc0[d], c0, w0);
            acc1[d] = fmaf(acc1[d], c1e, w1);
        }
    }

    // ---- staged folds: same-launch columns [rs0, rs_lv), sub-level by sub-level
    for (int gp = 0; gp < g; ++gp) {
        if (tid == 0) {
            int need = grp.ns[gp];
            int* fl = &lvflags[(grp.lv0 + gp) * 2 + mesh];
            int guard = 0;
            while (__hip_atomic_load(fl, __ATOMIC_RELAXED, __HIP_MEMORY_SCOPE_AGENT) < need
                   && guard < (1 << 22)) {
                __builtin_amdgcn_s_sleep(4);
                ++guard;
            }
        }
        __syncthreads();                           // all lanes ordered after flag observation
        int frs = grp.rs[gp], fre = grp.re[gp];
        for (int p = frs + sub; p < fre; p += 32) {
            float* kc = stgK + ((size_t)mesh * F + p) * C + head * DH;
            float* vc = stgV + ((size_t)mesh * F + p) * C + head * DH;
            float s0v = 0.f, s1v = 0.f;
            #pragma unroll
            for (int d = 0; d < DH; ++d) {
                float kd = __hip_atomic_load(kc + d, __ATOMIC_RELAXED, __HIP_MEMORY_SCOPE_AGENT);
                s0v = fmaf(q0[d], kd, s0v);
                s1v = fmaf(q1[d], kd, s1v);
            }
            float vv[DH];
            #pragma unroll
            for (int d = 0; d < DH; ++d)
                vv[d] = __hip_atomic_load(vc + d, __ATOMIC_RELAXED, __HIP_MEMORY_SCOPE_AGENT);
            {   // fold query 0
                float mn = fmaxf(m0, s0v);
                float c = __expf(m0 - mn), pw = __expf(s0v - mn);
                l0 = l0 * c + pw;
                #pragma unroll
                for (int d = 0; d < DH; ++d) acc0[d] = fmaf(acc0[d], c, pw * vv[d]);
                m0 = mn;
            }
            {   // fold query 1
                float mn = fmaxf(m1, s1v);
                float c = __expf(m1 - mn), pw = __expf(s1v - mn);
                l1 = l1 * c + pw;
                #pragma unroll
                for (int d = 0; d < DH; ++d) acc1[d] = fmaf(acc1[d], c, pw * vv[d]);
                m1 = mn;
            }
        }
    }

    // ---- merge 32 per-lane states per head
    #pragma unroll
    for (int w = 16; w >= 1; w >>= 1) {
        float mo = __shfl_xor(m0, w), lo = __shfl_xor(l0, w);
        float mn = fmaxf(m0, mo);
        float ca = __expf(m0 - mn), cb = __expf(mo - mn);
        l0 = l0 * ca + lo * cb;
        #pragma unroll
        for (int d = 0; d < DH; ++d) {
            float ao = __shfl_xor(acc0[d], w);
            acc0[d] = acc0[d] * ca + ao * cb;
        }
        m0 = mn;
        mo = __shfl_xor(m1, w); lo = __shfl_xor(l1, w);
        mn = fmaxf(m1, mo);
        ca = __expf(m1 - mn); cb = __expf(mo - mn);
        l1 = l1 * ca + lo * cb;
        #pragma unroll
        for (int d = 0; d < DH; ++d) {
            float ao = __shfl_xor(acc1[d], w);
            acc1[d] = acc1[d] * ca + ao * cb;
        }
        m1 = mn;
    }
    if (sub == 0) {
        // merge with the precomputed static state over [rs_lv, F)
        {
            int fr = a0 ? face0 : 0;
            const float* S = smS + (size_t)(mesh * F + fr) * SMH + head * 18;
            float ms = S[0], ls = S[1];
            float mn = fmaxf(m0, ms);
            float ca = __expf(m0 - mn), cb = __expf(ms - mn);
            sL[0][head] = l0 * ca + ls * cb;
            #pragma unroll
            for (int d = 0; d < DH; ++d)
                sRed[0][head * DH + d] = fmaf(acc0[d], ca, S[2 + d] * cb);
        }
        {
            int fr = a1 ? face1 : 0;
            const float* S = smS + (size_t)(mesh * F + fr) * SMH + head * 18;
            float ms = S[0], ls = S[1];
            float mn = fmaxf(m1, ms);
            float ca = __expf(m1 - mn), cb = __expf(ms - mn);
            sL[1][head] = l1 * ca + ls * cb;
            #pragma unroll
            for (int d = 0; d < DH; ++d)
                sRed[1][head * DH + d] = fmaf(acc1[d], ca, S[2 + d] * cb);
        }
    }
    __syncthreads();
    if (tid < C) sRed[0][tid] = sRed[0][tid] / sL[0][tid >> 4];
    else { int c = tid - C; sRed[1][c] = sRed[1][c] / sL[1][c >> 4]; }
    __syncthreads();

    // ---- epilogue: out-proj + resid, K/V refresh (normal stores for future launches,
    //      atomic staging stores + release flag for same-launch consumers)
    bool doStage = (g != GLV - 1);
    #pragma unroll 1
    for (int j = 0; j < 2; ++j) {
        bool act = j == 0 ? a0 : a1;
        if (!act) continue;
        size_t rowj = j == 0 ? row0 : row1;
        int facej = j == 0 ? face0 : face1;
        if (tid < C) {
            float o = 0.f;
            for (int k = 0; k < C; ++k) o = fmaf(sRed[j][k], Wo[k * C + tid], o);
            float nv = sQ[j][tid] + o;
            sNew[tid] = nv;
            cur[rowj + tid] = nv;
        }
        __syncthreads();
        int p = permIdx[facej];
        if (tid < C) {
            float a = 0.f;
            for (int k = 0; k < C; ++k) a = fmaf(sNew[k], Wk[k * C + tid], a);
            khT[((size_t)mesh * C + tid) * F + p] = a;
            if (doStage)
                __hip_atomic_store(stgK + ((size_t)mesh * F + p) * C + tid, a,
                                   __ATOMIC_RELAXED, __HIP_MEMORY_SCOPE_AGENT);
        } else {
            int c = tid - C;
            float a = 0.f;
            for (int k = 0; k < C; ++k) a = fmaf(sNew[k], Wv[k * C + c], a);
            vhT[((size_t)mesh * C + c) * F + p] = a;
            if (doStage)
                __hip_atomic_store(stgV + ((size_t)mesh * F + p) * C + c, a,
                                   __ATOMIC_RELAXED, __HIP_MEMORY_SCOPE_AGENT);
        }
        __syncthreads();                           // drains all waves' stores before flag
    }
    if (doStage && tid == 0)
        __hip_atomic_fetch_add(&lvflags[lv * 2 + mesh], 1,
                               __ATOMIC_RELEASE, __HIP_MEMORY_SCOPE_AGENT);
}

// ---------------------------------------------------------------- K4: 5-layer MLP + sigmoid (8 rows/block)
__global__ __launch_bounds__(256) void k_mlp(
        const float* __restrict__ cur,
        const float* __restrict__ W1, const float* __restrict__ b1,
        const float* __restrict__ W2, const float* __restrict__ b2,
        const float* __restrict__ W3, const float* __restrict__ b3,
        const float* __restrict__ W4, const float* __restrict__ b4,
        const float* __restrict__ W5, const float* __restrict__ b5,
        float* __restrict__ out_scores) {
    __shared__ float sIn[8][C];
    __shared__ float sA[8][WID];
    __shared__ float sB[8][WID];
    int tid = threadIdx.x;                        // 0..255
    int r0 = blockIdx.x * 8;
    for (int i = tid; i < 8 * C; i += 256) sIn[i >> 7][i & 127] = cur[(size_t)r0 * C + i];
    __syncthreads();
    {
        float a[8];
        #pragma unroll
        for (int r = 0; r < 8; ++r) a[r] = 0.f;
        for (int k = 0; k < C; ++k) {
            float w = W1[k * WID + tid];
            #pragma unroll
            for (int r = 0; r < 8; ++r) a[r] = fmaf(sIn[r][k], w, a[r]);
        }
        float bias = b1[tid];
        #pragma unroll
        for (int r = 0; r < 8; ++r) sA[r][tid] = fmaxf(a[r] + bias, 0.f);
    }
    __syncthreads();
    {
        float a[8];
        #pragma unroll
        for (int r = 0; r < 8; ++r) a[r] = 0.f;
        for (int k = 0; k < WID; ++k) {
            float w = W2[k * WID + tid];
            #pragma unroll
            for (int r = 0; r < 8; ++r) a[r] = fmaf(sA[r][k], w, a[r]);
        }
        float bias = b2[tid];
        #pragma unroll
        for (int r = 0; r < 8; ++r) sB[r][tid] = fmaxf(a[r] + bias, 0.f);
    }
    __syncthreads();
    {
        float a[8];
        #pragma unroll
        for (int r = 0; r < 8; ++r) a[r] = 0.f;
        for (int k = 0; k < WID; ++k) {
            float w = W3[k * WID + tid];
            #pragma unroll
            for (int r = 0; r < 8; ++r) a[r] = fmaf(sB[r][k], w, a[r]);
        }
        float bias = b3[tid];
        #pragma unroll
        for (int r = 0; r < 8; ++r) sA[r][tid] = fmaxf(a[r] + bias, 0.f);
    }
    __syncthreads();
    {
        float a[8];
        #pragma unroll
        for (int r = 0; r < 8; ++r) a[r] = 0.f;
        for (int k = 0; k < WID; ++k) {
            float w = W4[k * WID + tid];
            #pragma unroll
            for (int r = 0; r < 8; ++r) a[r] = fmaf(sA[r][k], w, a[r]);
        }
        float bias = b4[tid];
        #pragma unroll
        for (int r = 0; r < 8; ++r) sB[r][tid] = fmaxf(a[r] + bias, 0.f);
    }
    __syncthreads();
    if (tid < 8) {
        float a = b5[0];
        for (int k = 0; k < WID; ++k) a = fmaf(sB[tid][k], W5[k], a);
        out_scores[r0 + tid] = 1.f / (1.f + __expf(-a));
    }
}

// ---------------------------------------------------------------- K5: cur[B,F,C] f32 -> out0[B,C,F] f32
__global__ void k_transpose_out(const float* __restrict__ cur, float* __restrict__ out) {
    __shared__ float tile[32][33];
    int b = blockIdx.z;
    int f0 = blockIdx.x * 32, c0 = blockIdx.y * 32;
    int tx = threadIdx.x, ty = threadIdx.y;
    #pragma unroll
    for (int i = 0; i < 4; ++i) {
        int f = f0 + ty + i * 8;
        tile[ty + i * 8][tx] = cur[((size_t)b * F + f) * C + c0 + tx];
    }
    __syncthreads();
    #pragma unroll
    for (int i = 0; i < 4; ++i) {
        int c = c0 + ty + i * 8;
        out[((size_t)b * C + c) * F + f0 + tx] = tile[tx][ty + i * 8];
    }
}

// ----------------------------------------------------------------
extern "C" void kernel_launch(void* const* d_in, const int* in_sizes, int n_in,
                              void* d_out, int out_size, void* d_ws, size_t ws_size,
                              hipStream_t stream) {
    const int* levels = (const int*)d_in[15];
    int Bd = in_sizes[15] / NLV;                  // ring capacity per level

    const size_t n = (size_t)NB * F * C;          // 589824
    float* cur  = (float*)d_ws;
    float* qh   = cur + n;
    float* khT  = qh + n;
    float* vhT  = khT + n;
    float* wbuf = vhT + n;                        // fp32 weight copies, 296193 floats
    int*   permIdx = (int*)(wbuf + 296193 + 3);
    int*   flag = permIdx + F;                    // 1 int (dtype flag)
    int*   lvflags = flag + 1;                    // 2*NLV ints (level-done flags)
    float* smS  = (float*)(permIdx + 2404);       // static softmax state: NB*F*SMH floats
    float* stgK = smS + (size_t)NB * F * SMH;     // staged K cols: NB*F*C floats
    float* stgV = stgK + n;                       // staged V cols: NB*F*C floats

    const int oWq = 0,       oWk = 16384,  oWv = 32768,  oWo = 49152;
    const int oW1 = 65536,   oB1 = 98304;
    const int oW2 = 98560,   oB2 = 164096;
    const int oW3 = 164352,  oB3 = 229888;
    const int oW4 = 230144,  oB4 = 295680;
    const int oW5 = 295936,  oB5 = 296192;
    const int wtot = 296193;

    WSegs segs = {{
        { d_in[1],  oWq, 16384 }, { d_in[2],  oWk, 16384 },
        { d_in[3],  oWv, 16384 }, { d_in[4],  oWo, 16384 },
        { d_in[5],  oW1, 32768 }, { d_in[6],  oB1, 256 },
        { d_in[7],  oW2, 65536 }, { d_in[8],  oB2, 256 },
        { d_in[9],  oW3, 65536 }, { d_in[10], oB3, 256 },
        { d_in[11], oW4, 65536 }, { d_in[12], oB4, 256 },
        { d_in[13], oW5, 256 },   { d_in[14], oB5, 1 },
    }};

    // host-side ring prefix + pair prefix (pure function of GRIDN; matches k_permdetect)
    Rings rings;
    Pairs pairs;
    int totPairs = 0;
    {
        int cnt[NLV];
        for (int l = 0; l < NLV; ++l) cnt[l] = 0;
        for (int i = 0; i < GRIDN; ++i)
            for (int j = 0; j < GRIDN; ++j)
                cnt[(i < 24 ? 24 - i : i - 24) + (j < 24 ? 24 - j : j - 24)]++;
        rings.v[0] = 0;
        pairs.v[0] = 0;
        for (int l = 0; l < NLV; ++l) {
            rings.v[l + 1] = rings.v[l] + cnt[l];
            pairs.v[l + 1] = pairs.v[l] + (cnt[l] + 1) / 2;
        }
        totPairs = pairs.v[NLV];
    }

    float* out0 = (float*)d_out;                  // final.transpose(0,2,1): [B,C,F] fp32
    float* out1 = out0 + (size_t)NB * C * F;      // scores: [B,F,1] fp32

    k_permdetect<<<1, 256, 0, stream>>>(d_in[0], flag, permIdx, lvflags);
    k_convert<<<(wtot + 255) / 256, 256, 0, stream>>>(segs, flag, wbuf, wtot);
    k_transpose_in<<<dim3(F / 32, C / 32, NB), dim3(32, 8), 0, stream>>>(d_in[0], flag, cur);
    k_proj_init<<<(NB * F) / 8, 128, 0, stream>>>(cur, permIdx, wbuf + oWq, wbuf + oWk, wbuf + oWv,
                                                  qh, khT, vhT);

    // static partials for ALL queries at once (khT/vhT still pristine here)
    k_static<<<2 * totPairs, 256, 0, stream>>>(Bd, rings, pairs, levels, qh, khT, vhT, smS);

    // 7 launches of 7 levels each
    for (int lv0 = 0; lv0 < NLV; lv0 += GLV) {
        Grp grp;
        grp.lv0 = lv0;
        grp.rs0 = rings.v[lv0];
        grp.bofs[0] = 0;
        for (int g = 0; g < GLV; ++g) {
            int lv = lv0 + g;
            int rs = rings.v[lv], re = rings.v[lv + 1];
            int ns = (re - rs + 1) / 2;
            grp.rs[g] = rs;
            grp.re[g] = re;
            grp.ns[g] = ns;
            grp.bofs[g + 1] = grp.bofs[g] + 2 * ns;
        }
        k_group<<<grp.bofs[GLV], 256, 0, stream>>>(Bd, grp, levels, permIdx, qh, cur,
                                                   khT, vhT, smS,
                                                   wbuf + oWk, wbuf + oWv, wbuf + oWo,
                                                   stgK, stgV, lvflags);
    }

    k_mlp<<<(NB * F) / 8, 256, 0, stream>>>(cur, wbuf + oW1, wbuf + oB1, wbuf + oW2, wbuf + oB2,
                                            wbuf + oW3, wbuf + oB3, wbuf + oW4, wbuf + oB4,
                                            wbuf + oW5, wbuf + oB5, out1);
    k_transpose_out<<<dim3(F / 32, C / 32, NB), dim3(32, 8), 0, stream>>>(cur, out0);
}

// Round 5
// 1526.288 us; speedup vs baseline: 2.9544x; 1.0335x over previous
//
#include <hip/hip_runtime.h>
#include <hip/hip_bf16.h>
#include <stdint.h>

#define GRIDN 48
#define F 2304
#define C 128
#define H 8
#define DH 16
#define NB 2          // batch (meshes)
#define WID 256
#define NLV 49        // BFS levels for GRID=48, anchor at (24,24)
#define SMH (H * 18)  // per-face static-softmax state: 8 heads x {m, l, acc[16]}
#define GLV 7         // levels per k_group launch (49 = 7 x 7)

typedef __hip_bfloat16 bf16;

__device__ __forceinline__ float b2f(bf16 v) { return __bfloat162float(v); }

// ---------------------------------------------------------------- K0: dtype detect + BFS-ring perm + flag clear
__global__ void k_permdetect(const void* __restrict__ x, int* __restrict__ flag,
                             int* __restrict__ permIdx, int* __restrict__ lvflags) {
    __shared__ int cnt[NLV], start[NLV];
    __shared__ int bad;
    int t = threadIdx.x;
    if (t == 0) bad = 0;
    if (t < NLV) cnt[t] = 0;
    for (int i = t; i < 2 * NLV; i += 256) lvflags[i] = 0;
    __syncthreads();
    {   // dtype detect on first 2048 elements
        const bf16* xb = (const bf16*)x;
        int insane = 0;
        #pragma unroll
        for (int i = 0; i < 8; ++i) {
            float v = b2f(xb[t * 8 + i]);
            if (!(fabsf(v) < 1e10f)) insane = 1;
        }
        if (insane) atomicOr(&bad, 1);
    }
    for (int f = t; f < F; f += 256) {
        int d = abs(f / GRIDN - GRIDN / 2) + abs(f % GRIDN - GRIDN / 2);
        atomicAdd(&cnt[d], 1);
    }
    __syncthreads();
    if (t == 0) {
        int s = 0;
        for (int l = 0; l < NLV; ++l) { start[l] = s; s += cnt[l]; }
        *flag = bad;
    }
    __syncthreads();
    for (int f = t; f < F; f += 256) {
        int d = abs(f / GRIDN - GRIDN / 2) + abs(f % GRIDN - GRIDN / 2);
        permIdx[f] = atomicAdd(&start[d], 1);
    }
}

// ---------------------------------------------------------------- K0b: convert all weights/biases to fp32
struct WSeg { const void* src; int off; int cnt; };
struct WSegs { WSeg s[14]; };

__global__ void k_convert(WSegs segs, const int* __restrict__ flag,
                          float* __restrict__ dst, int total) {
    int i = blockIdx.x * blockDim.x + threadIdx.x;
    if (i >= total) return;
    bool f32 = (*flag != 0);
    #pragma unroll 1
    for (int j = 0; j < 14; ++j) {
        int off = segs.s[j].off, cnt = segs.s[j].cnt;
        if (i >= off && i < off + cnt) {
            int k = i - off;
            dst[i] = f32 ? ((const float*)segs.s[j].src)[k]
                         : b2f(((const bf16*)segs.s[j].src)[k]);
            return;
        }
    }
}

// ---------------------------------------------------------------- K0c: transposed weight copies for the epilogue
// wT[m][c][k] = W_m[k][c] for m in {Wk, Wv, Wo} -> per-output-channel rows, float4-streamable.
__global__ void k_wtrans(const float* __restrict__ Wk, const float* __restrict__ Wv,
                         const float* __restrict__ Wo, float* __restrict__ wT) {
    int m = blockIdx.y;
    const float* s = m == 0 ? Wk : (m == 1 ? Wv : Wo);
    int c = blockIdx.x;
    int k = threadIdx.x;
    wT[((size_t)m * C + c) * C + k] = s[k * C + c];
}

// ---------------------------------------------------------------- K1: x[B,C,F] -> cur[B,F,C] f32
__global__ void k_transpose_in(const void* __restrict__ x, const int* __restrict__ flag,
                               float* __restrict__ cur) {
    __shared__ float tile[32][33];
    bool f32 = (*flag != 0);
    int b = blockIdx.z;
    int f0 = blockIdx.x * 32, c0 = blockIdx.y * 32;
    int tx = threadIdx.x, ty = threadIdx.y;            // 32 x 8
    #pragma unroll
    for (int i = 0; i < 4; ++i) {
        int c = c0 + ty + i * 8;
        size_t idx = ((size_t)b * C + c) * F + f0 + tx;
        tile[ty + i * 8][tx] = f32 ? ((const float*)x)[idx] : b2f(((const bf16*)x)[idx]);
    }
    __syncthreads();
    #pragma unroll
    for (int i = 0; i < 4; ++i) {
        int f = f0 + ty + i * 8;
        cur[((size_t)b * F + f) * C + c0 + tx] = tile[tx][ty + i * 8];
    }
}

// ---------------------------------------------------------------- K2: init projections (2 rows/block for occupancy)
__global__ __launch_bounds__(128) void k_proj_init(
        const float* __restrict__ cur, const int* __restrict__ permIdx,
        const float* __restrict__ Wq, const float* __restrict__ Wk, const float* __restrict__ Wv,
        float* __restrict__ qh, float* __restrict__ khT, float* __restrict__ vhT) {
    __shared__ float rows[2][C];
    int r0 = blockIdx.x * 2;
    int tid = threadIdx.x;  // 0..127 = output channel
    rows[0][tid] = cur[(size_t)r0 * C + tid];
    rows[1][tid] = cur[(size_t)(r0 + 1) * C + tid];
    __syncthreads();
    float aq0 = 0.f, aq1 = 0.f, ak0 = 0.f, ak1 = 0.f, av0 = 0.f, av1 = 0.f;
    for (int k = 0; k < C; ++k) {
        float wq = Wq[k * C + tid];
        float wk = Wk[k * C + tid];
        float wv = Wv[k * C + tid];
        float x0 = rows[0][k], x1 = rows[1][k];
        aq0 = fmaf(x0, wq, aq0); aq1 = fmaf(x1, wq, aq1);
        ak0 = fmaf(x0, wk, ak0); ak1 = fmaf(x1, wk, ak1);
        av0 = fmaf(x0, wv, av0); av1 = fmaf(x1, wv, av1);
    }
    const float scale = 0.25f;  // 1/sqrt(DH)
    #pragma unroll
    for (int r = 0; r < 2; ++r) {
        int grow = r0 + r;
        int mesh = grow / F, face = grow % F;
        int p = permIdx[face];
        qh[(size_t)grow * C + tid] = (r == 0 ? aq0 : aq1) * scale;
        khT[((size_t)mesh * C + tid) * F + p] = r == 0 ? ak0 : ak1;
        vhT[((size_t)mesh * C + tid) * F + p] = r == 0 ? av0 : av1;
    }
}

struct Rings { int v[NLV + 1]; };
struct Pairs { int v[NLV + 1]; };

// ---------------------------------------------------------------- K2c: static attention partials.
// (unchanged — runs on pristine khT/vhT, covers key columns [rs_lv, F) per query)
__global__ __launch_bounds__(256) void k_static(
        int Bd, Rings rings, Pairs pairs,
        const int* __restrict__ levels,
        const float* __restrict__ qh_all,
        const float* __restrict__ khT, const float* __restrict__ vhT,
        float* __restrict__ smS) {
    int bx = blockIdx.x;
    int mesh = bx & 1;
    int gp = bx >> 1;
    int lv = 0;
    while (gp >= pairs.v[lv + 1]) ++lv;
    int spair = gp - pairs.v[lv];
    int rs = rings.v[lv];
    int s0 = spair * 2, s1 = s0 + 1;
    int face0 = (s0 < Bd) ? levels[lv * Bd + s0] : F;
    int face1 = (s1 < Bd) ? levels[lv * Bd + s1] : F;
    bool a0 = (face0 >= 0 && face0 < F), a1 = (face1 >= 0 && face1 < F);
    if (!a0 && !a1) return;

    __shared__ float sQh[2][C];
    int tid = threadIdx.x;
    size_t row0 = ((size_t)mesh * F + face0) * C;
    size_t row1 = ((size_t)mesh * F + face1) * C;
    if (tid < C) sQh[0][tid] = a0 ? qh_all[row0 + tid] : 0.f;
    else { int c = tid - C; sQh[1][c] = a1 ? qh_all[row1 + c] : 0.f; }
    __syncthreads();

    int head = tid >> 5, sub = tid & 31;
    float q0[DH], q1[DH];
    #pragma unroll
    for (int d = 0; d < DH; ++d) { q0[d] = sQh[0][head * DH + d]; q1[d] = sQh[1][head * DH + d]; }

    const float* Kb = khT + ((size_t)mesh * C + head * DH) * F;
    const float* Vb = vhT + ((size_t)mesh * C + head * DH) * F;

    float m0 = -1e30f, l0 = 0.f, m1 = -1e30f, l1 = 0.f;
    float acc0[DH], acc1[DH];
    #pragma unroll
    for (int d = 0; d < DH; ++d) { acc0[d] = 0.f; acc1[d] = 0.f; }

    int base0 = rs & ~127;
    for (int base = base0; base < F; base += 128) {
        int p4 = base + 4 * sub;
        float sx0 = 0, sy0 = 0, sz0 = 0, sw0 = 0;
        float sx1 = 0, sy1 = 0, sz1 = 0, sw1 = 0;
        #pragma unroll
        for (int d = 0; d < DH; ++d) {
            float4 kk = *(const float4*)(Kb + d * F + p4);
            float a = q0[d], b = q1[d];
            sx0 = fmaf(a, kk.x, sx0); sy0 = fmaf(a, kk.y, sy0);
            sz0 = fmaf(a, kk.z, sz0); sw0 = fmaf(a, kk.w, sw0);
            sx1 = fmaf(b, kk.x, sx1); sy1 = fmaf(b, kk.y, sy1);
            sz1 = fmaf(b, kk.z, sz1); sw1 = fmaf(b, kk.w, sw1);
        }
        float g0 = 1.f, g1 = 1.f, g2 = 1.f, g3 = 1.f;
        if (base < rs) {
            g0 = (p4     >= rs) ? 1.f : 0.f; g1 = (p4 + 1 >= rs) ? 1.f : 0.f;
            g2 = (p4 + 2 >= rs) ? 1.f : 0.f; g3 = (p4 + 3 >= rs) ? 1.f : 0.f;
        }
        float mx0 = fmaxf(fmaxf(sx0, sy0), fmaxf(sz0, sw0));
        float mn0 = fmaxf(m0, mx0);
        float c0 = __expf(m0 - mn0);
        float px0 = __expf(sx0 - mn0) * g0, py0 = __expf(sy0 - mn0) * g1;
        float pz0 = __expf(sz0 - mn0) * g2, pw0 = __expf(sw0 - mn0) * g3;
        l0 = fmaf(l0, c0, px0 + py0 + pz0 + pw0);
        m0 = mn0;
        float mx1 = fmaxf(fmaxf(sx1, sy1), fmaxf(sz1, sw1));
        float mn1 = fmaxf(m1, mx1);
        float c1e = __expf(m1 - mn1);
        float px1 = __expf(sx1 - mn1) * g0, py1 = __expf(sy1 - mn1) * g1;
        float pz1 = __expf(sz1 - mn1) * g2, pw1 = __expf(sw1 - mn1) * g3;
        l1 = fmaf(l1, c1e, px1 + py1 + pz1 + pw1);
        m1 = mn1;
        #pragma unroll
        for (int d = 0; d < DH; ++d) {
            float4 vv = *(const float4*)(Vb + d * F + p4);
            float w0 = fmaf(px0, vv.x, fmaf(py0, vv.y, fmaf(pz0, vv.z, pw0 * vv.w)));
            float w1 = fmaf(px1, vv.x, fmaf(py1, vv.y, fmaf(pz1, vv.z, pw1 * vv.w)));
            acc0[d] = fmaf(acc0[d], c0, w0);
            acc1[d] = fmaf(acc1[d], c1e, w1);
        }
    }

    #pragma unroll
    for (int w = 16; w >= 1; w >>= 1) {
        float mo = __shfl_xor(m0, w), lo = __shfl_xor(l0, w);
        float mn = fmaxf(m0, mo);
        float ca = __expf(m0 - mn), cb = __expf(mo - mn);
        l0 = l0 * ca + lo * cb;
        #pragma unroll
        for (int d = 0; d < DH; ++d) {
            float ao = __shfl_xor(acc0[d], w);
            acc0[d] = acc0[d] * ca + ao * cb;
        }
        m0 = mn;
        mo = __shfl_xor(m1, w); lo = __shfl_xor(l1, w);
        mn = fmaxf(m1, mo);
        ca = __expf(m1 - mn); cb = __expf(mo - mn);
        l1 = l1 * ca + lo * cb;
        #pragma unroll
        for (int d = 0; d < DH; ++d) {
            float ao = __shfl_xor(acc1[d], w);
            acc1[d] = acc1[d] * ca + ao * cb;
        }
        m1 = mn;
    }
    if (sub == 0) {
        if (a0) {
            float* S = smS + (size_t)(mesh * F + face0) * SMH + head * 18;
            S[0] = m0; S[1] = l0;
            #pragma unroll
            for (int d = 0; d < DH; ++d) S[2 + d] = acc0[d];
        }
        if (a1) {
            float* S = smS + (size_t)(mesh * F + face1) * SMH + head * 18;
            S[0] = m1; S[1] = l1;
            #pragma unroll
            for (int d = 0; d < DH; ++d) S[2 + d] = acc1[d];
        }
    }
}

// ---------------------------------------------------------------- K3: GLV BFS levels per launch.
// Same flag-chained structure as round 4; epilogue rewritten on transposed weights (float4 rows,
// both queries in parallel), staged folds use 64-bit relaxed agent atomics.
struct Grp { int lv0; int rs0; int bofs[GLV + 1]; int rs[GLV]; int re[GLV]; int ns[GLV]; };

__global__ __launch_bounds__(256, 3) void k_group(
        int Bd, Grp grp,
        const int* __restrict__ levels, const int* __restrict__ permIdx,
        const float* __restrict__ qh_all, float* __restrict__ cur,
        float* __restrict__ khT, float* __restrict__ vhT,
        const float* __restrict__ smS,
        const float* __restrict__ WkT, const float* __restrict__ WvT,
        const float* __restrict__ WoT,
        float* __restrict__ stgK, float* __restrict__ stgV,
        int* __restrict__ lvflags) {
    int bx = blockIdx.x;
    int g = 0;
    while (bx >= grp.bofs[g + 1]) ++g;            // sub-level (monotone in blockIdx)
    int lb = bx - grp.bofs[g];
    int mesh = lb & 1;
    int spair = lb >> 1;
    int lv = grp.lv0 + g;
    int rs0 = grp.rs0;

    int s0 = spair * 2, s1 = s0 + 1;
    int face0 = (s0 < Bd) ? levels[lv * Bd + s0] : F;
    int face1 = (s1 < Bd) ? levels[lv * Bd + s1] : F;
    bool a0 = (face0 >= 0 && face0 < F), a1 = (face1 >= 0 && face1 < F);

    __shared__ __attribute__((aligned(16))) float sQh[2][C], sQ[2][C], sRed[2][C], sNew2[2][C];
    __shared__ float sL[2][H];
    int tid = threadIdx.x;
    size_t row0 = ((size_t)mesh * F + face0) * C;
    size_t row1 = ((size_t)mesh * F + face1) * C;
    if (tid < C) {
        if (a0) { sQ[0][tid] = cur[row0 + tid]; sQh[0][tid] = qh_all[row0 + tid]; }
        else    { sQ[0][tid] = 0.f; sQh[0][tid] = 0.f; }
    } else {
        int c = tid - C;
        if (a1) { sQ[1][c] = cur[row1 + c]; sQh[1][c] = qh_all[row1 + c]; }
        else    { sQ[1][c] = 0.f; sQh[1][c] = 0.f; }
    }
    __syncthreads();

    int head = tid >> 5, sub = tid & 31;
    float q0[DH], q1[DH];
    #pragma unroll
    for (int d = 0; d < DH; ++d) { q0[d] = sQh[0][head * DH + d]; q1[d] = sQh[1][head * DH + d]; }

    const float* Kb = khT + ((size_t)mesh * C + head * DH) * F;
    const float* Vb = vhT + ((size_t)mesh * C + head * DH) * F;

    float m0 = -1e30f, l0 = 0.f, m1 = -1e30f, l1 = 0.f;
    float acc0[DH], acc1[DH];
    #pragma unroll
    for (int d = 0; d < DH; ++d) { acc0[d] = 0.f; acc1[d] = 0.f; }

    // ---- main stream: prior-launch columns [0, rs0)
    for (int base = 0; base < rs0; base += 128) {
        int p4 = base + 4 * sub;
        float sx0 = 0, sy0 = 0, sz0 = 0, sw0 = 0;
        float sx1 = 0, sy1 = 0, sz1 = 0, sw1 = 0;
        #pragma unroll
        for (int d = 0; d < DH; ++d) {
            float4 kk = *(const float4*)(Kb + d * F + p4);
            float a = q0[d], b = q1[d];
            sx0 = fmaf(a, kk.x, sx0); sy0 = fmaf(a, kk.y, sy0);
            sz0 = fmaf(a, kk.z, sz0); sw0 = fmaf(a, kk.w, sw0);
            sx1 = fmaf(b, kk.x, sx1); sy1 = fmaf(b, kk.y, sy1);
            sz1 = fmaf(b, kk.z, sz1); sw1 = fmaf(b, kk.w, sw1);
        }
        float g0 = 1.f, g1 = 1.f, g2 = 1.f, g3 = 1.f;
        if (base + 128 > rs0) {
            g0 = (p4     < rs0) ? 1.f : 0.f; g1 = (p4 + 1 < rs0) ? 1.f : 0.f;
            g2 = (p4 + 2 < rs0) ? 1.f : 0.f; g3 = (p4 + 3 < rs0) ? 1.f : 0.f;
        }
        float mx0 = fmaxf(fmaxf(sx0, sy0), fmaxf(sz0, sw0));
        float mn0 = fmaxf(m0, mx0);
        float c0 = __expf(m0 - mn0);
        float px0 = __expf(sx0 - mn0) * g0, py0 = __expf(sy0 - mn0) * g1;
        float pz0 = __expf(sz0 - mn0) * g2, pw0 = __expf(sw0 - mn0) * g3;
        l0 = fmaf(l0, c0, px0 + py0 + pz0 + pw0);
        m0 = mn0;
        float mx1 = fmaxf(fmaxf(sx1, sy1), fmaxf(sz1, sw1));
        float mn1 = fmaxf(m1, mx1);
        float c1e = __expf(m1 - mn1);
        float px1 = __expf(sx1 - mn1) * g0, py1 = __expf(sy1 - mn1) * g1;
        float pz1 = __expf(sz1 - mn1) * g2, pw1 = __expf(sw1 - mn1) * g3;
        l1 = fmaf(l1, c1e, px1 + py1 + pz1 + pw1);
        m1 = mn1;
        #pragma unroll
        for (int d = 0; d < DH; ++d) {
            float4 vv = *(const float4*)(Vb + d * F + p4);
            float w0 = fmaf(px0, vv.x, fmaf(py0, vv.y, fmaf(pz0, vv.z, pw0 * vv.w)));
            float w1 = fmaf(px1, vv.x, fmaf(py1, vv.y, fmaf(pz1, vv.z, pw1 * vv.w)));
            acc0[d] = fmaf(acc0[d], c0, w0);
            acc1[d] = fmaf(acc1[d], c1e, w1);
        }
    }

    // ---- staged folds: same-launch columns [rs0, rs_lv), sub-level by sub-level
    for (int gp = 0; gp < g; ++gp) {
        if (tid == 0) {
            int need = grp.ns[gp];
            int* fl = &lvflags[(grp.lv0 + gp) * 2 + mesh];
            int guard = 0;
            while (__hip_atomic_load(fl, __ATOMIC_RELAXED, __HIP_MEMORY_SCOPE_AGENT) < need
                   && guard < (1 << 22)) {
                __builtin_amdgcn_s_sleep(4);
                ++guard;
            }
        }
        __syncthreads();                           // all lanes ordered after flag observation
        int frs = grp.rs[gp], fre = grp.re[gp];
        for (int p = frs + sub; p < fre; p += 32) {
            const unsigned long long* kc =
                (const unsigned long long*)(stgK + ((size_t)mesh * F + p) * C + head * DH);
            const unsigned long long* vc =
                (const unsigned long long*)(stgV + ((size_t)mesh * F + p) * C + head * DH);
            float s0v = 0.f, s1v = 0.f;
            #pragma unroll
            for (int d2 = 0; d2 < DH / 2; ++d2) {
                unsigned long long kw = __hip_atomic_load(kc + d2, __ATOMIC_RELAXED,
                                                          __HIP_MEMORY_SCOPE_AGENT);
                float2 kf = *(float2*)&kw;
                s0v = fmaf(q0[2 * d2], kf.x, s0v); s0v = fmaf(q0[2 * d2 + 1], kf.y, s0v);
                s1v = fmaf(q1[2 * d2], kf.x, s1v); s1v = fmaf(q1[2 * d2 + 1], kf.y, s1v);
            }
            float vv[DH];
            #pragma unroll
            for (int d2 = 0; d2 < DH / 2; ++d2) {
                unsigned long long vw = __hip_atomic_load(vc + d2, __ATOMIC_RELAXED,
                                                          __HIP_MEMORY_SCOPE_AGENT);
                float2 vf = *(float2*)&vw;
                vv[2 * d2] = vf.x; vv[2 * d2 + 1] = vf.y;
            }
            {   // fold query 0
                float mn = fmaxf(m0, s0v);
                float c = __expf(m0 - mn), pw = __expf(s0v - mn);
                l0 = l0 * c + pw;
                #pragma unroll
                for (int d = 0; d < DH; ++d) acc0[d] = fmaf(acc0[d], c, pw * vv[d]);
                m0 = mn;
            }
            {   // fold query 1
                float mn = fmaxf(m1, s1v);
                float c = __expf(m1 - mn), pw = __expf(s1v - mn);
                l1 = l1 * c + pw;
                #pragma unroll
                for (int d = 0; d < DH; ++d) acc1[d] = fmaf(acc1[d], c, pw * vv[d]);
                m1 = mn;
            }
        }
    }

    // ---- merge 32 per-lane states per head
    #pragma unroll
    for (int w = 16; w >= 1; w >>= 1) {
        float mo = __shfl_xor(m0, w), lo = __shfl_xor(l0, w);
        float mn = fmaxf(m0, mo);
        float ca = __expf(m0 - mn), cb = __expf(mo - mn);
        l0 = l0 * ca + lo * cb;
        #pragma unroll
        for (int d = 0; d < DH; ++d) {
            float ao = __shfl_xor(acc0[d], w);
            acc0[d] = acc0[d] * ca + ao * cb;
        }
        m0 = mn;
        mo = __shfl_xor(m1, w); lo = __shfl_xor(l1, w);
        mn = fmaxf(m1, mo);
        ca = __expf(m1 - mn); cb = __expf(mo - mn);
        l1 = l1 * ca + lo * cb;
        #pragma unroll
        for (int d = 0; d < DH; ++d) {
            float ao = __shfl_xor(acc1[d], w);
            acc1[d] = acc1[d] * ca + ao * cb;
        }
        m1 = mn;
    }
    if (sub == 0) {
        // merge with the precomputed static state over [rs_lv, F)
        {
            int fr = a0 ? face0 : 0;
            const float* S = smS + (size_t)(mesh * F + fr) * SMH + head * 18;
            float ms = S[0], ls = S[1];
            float mn = fmaxf(m0, ms);
            float ca = __expf(m0 - mn), cb = __expf(ms - mn);
            sL[0][head] = l0 * ca + ls * cb;
            #pragma unroll
            for (int d = 0; d < DH; ++d)
                sRed[0][head * DH + d] = fmaf(acc0[d], ca, S[2 + d] * cb);
        }
        {
            int fr = a1 ? face1 : 0;
            const float* S = smS + (size_t)(mesh * F + fr) * SMH + head * 18;
            float ms = S[0], ls = S[1];
            float mn = fmaxf(m1, ms);
            float ca = __expf(m1 - mn), cb = __expf(ms - mn);
            sL[1][head] = l1 * ca + ls * cb;
            #pragma unroll
            for (int d = 0; d < DH; ++d)
                sRed[1][head * DH + d] = fmaf(acc1[d], ca, S[2 + d] * cb);
        }
    }
    __syncthreads();
    if (tid < C) sRed[0][tid] = sRed[0][tid] / sL[0][tid >> 4];
    else { int c = tid - C; sRed[1][c] = sRed[1][c] / sL[1][c >> 4]; }
    __syncthreads();

    // ---- epilogue (transposed weights): E1 out-proj + resid for BOTH queries in parallel,
    //      then per-query K/V refresh with K and V halves in parallel.
    bool doStage = (g != GLV - 1);
    {
        int j = tid >> 7;              // which query this half handles
        int c = tid & 127;
        bool act = j == 0 ? a0 : a1;
        float o = 0.f;
        const float4* WoR = (const float4*)(WoT + (size_t)c * C);
        const float4* Rr  = (const float4*)(&sRed[j][0]);
        #pragma unroll
        for (int k4 = 0; k4 < C / 4; ++k4) {
            float4 w = WoR[k4];
            float4 r = Rr[k4];
            o = fmaf(r.x, w.x, o); o = fmaf(r.y, w.y, o);
            o = fmaf(r.z, w.z, o); o = fmaf(r.w, w.w, o);
        }
        float nv = sQ[j][c] + o;
        sNew2[j][c] = nv;
        if (act) cur[(j == 0 ? row0 : row1) + c] = nv;
    }
    __syncthreads();
    #pragma unroll 1
    for (int j = 0; j < 2; ++j) {
        bool act = j == 0 ? a0 : a1;
        if (!act) continue;
        int facej = j == 0 ? face0 : face1;
        int p = permIdx[facej];
        int c = tid & 127;
        const float* WT = (tid < C) ? WkT : WvT;
        float a = 0.f;
        const float4* Wr = (const float4*)(WT + (size_t)c * C);
        const float4* Nr = (const float4*)(&sNew2[j][0]);
        #pragma unroll
        for (int k4 = 0; k4 < C / 4; ++k4) {
            float4 w = Wr[k4];
            float4 x = Nr[k4];
            a = fmaf(x.x, w.x, a); a = fmaf(x.y, w.y, a);
            a = fmaf(x.z, w.z, a); a = fmaf(x.w, w.w, a);
        }
        if (tid < C) {
            khT[((size_t)mesh * C + c) * F + p] = a;
            if (doStage)
                __hip_atomic_store(stgK + ((size_t)mesh * F + p) * C + c, a,
                                   __ATOMIC_RELAXED, __HIP_MEMORY_SCOPE_AGENT);
        } else {
            vhT[((size_t)mesh * C + c) * F + p] = a;
            if (doStage)
                __hip_atomic_store(stgV + ((size_t)mesh * F + p) * C + c, a,
                                   __ATOMIC_RELAXED, __HIP_MEMORY_SCOPE_AGENT);
        }
    }
    __syncthreads();                               // drains all waves' stores before flag
    if (doStage && tid == 0)
        __hip_atomic_fetch_add(&lvflags[lv * 2 + mesh], 1,
                               __ATOMIC_RELEASE, __HIP_MEMORY_SCOPE_AGENT);
}

// ---------------------------------------------------------------- K4: 5-layer MLP + sigmoid (2 rows/block)
__global__ __launch_bounds__(256) void k_mlp(
        const float* __restrict__ cur,
        const float* __restrict__ W1, const float* __restrict__ b1,
        const float* __restrict__ W2, const float* __restrict__ b2,
        const float* __restrict__ W3, const float* __restrict__ b3,
        const float* __restrict__ W4, const float* __restrict__ b4,
        const float* __restrict__ W5, const float* __restrict__ b5,
        float* __restrict__ out_scores) {
    __shared__ float sIn[2][C];
    __shared__ float sA[2][WID];
    __shared__ float sB[2][WID];
    int tid = threadIdx.x;                        // 0..255
    int r0 = blockIdx.x * 2;
    for (int i = tid; i < 2 * C; i += 256) sIn[i >> 7][i & 127] = cur[(size_t)r0 * C + i];
    __syncthreads();
    {
        float a0 = 0.f, a1 = 0.f;
        for (int k = 0; k < C; ++k) {
            float w = W1[k * WID + tid];
            a0 = fmaf(sIn[0][k], w, a0);
            a1 = fmaf(sIn[1][k], w, a1);
        }
        float bias = b1[tid];
        sA[0][tid] = fmaxf(a0 + bias, 0.f);
        sA[1][tid] = fmaxf(a1 + bias, 0.f);
    }
    __syncthreads();
    {
        float a0 = 0.f, a1 = 0.f;
        for (int k = 0; k < WID; ++k) {
            float w = W2[k * WID + tid];
            a0 = fmaf(sA[0][k], w, a0);
            a1 = fmaf(sA[1][k], w, a1);
        }
        float bias = b2[tid];
        sB[0][tid] = fmaxf(a0 + bias, 0.f);
        sB[1][tid] = fmaxf(a1 + bias, 0.f);
    }
    __syncthreads();
    {
        float a0 = 0.f, a1 = 0.f;
        for (int k = 0; k < WID; ++k) {
            float w = W3[k * WID + tid];
            a0 = fmaf(sB[0][k], w, a0);
            a1 = fmaf(sB[1][k], w, a1);
        }
        float bias = b3[tid];
        sA[0][tid] = fmaxf(a0 + bias, 0.f);
        sA[1][tid] = fmaxf(a1 + bias, 0.f);
    }
    __syncthreads();
    {
        float a0 = 0.f, a1 = 0.f;
        for (int k = 0; k < WID; ++k) {
            float w = W4[k * WID + tid];
            a0 = fmaf(sA[0][k], w, a0);
            a1 = fmaf(sA[1][k], w, a1);
        }
        float bias = b4[tid];
        sB[0][tid] = fmaxf(a0 + bias, 0.f);
        sB[1][tid] = fmaxf(a1 + bias, 0.f);
    }
    __syncthreads();
    if (tid < 2) {
        float a = b5[0];
        for (int k = 0; k < WID; ++k) a = fmaf(sB[tid][k], W5[k], a);
        out_scores[r0 + tid] = 1.f / (1.f + __expf(-a));
    }
}

// ---------------------------------------------------------------- K5: cur[B,F,C] f32 -> out0[B,C,F] f32
__global__ void k_transpose_out(const float* __restrict__ cur, float* __restrict__ out) {
    __shared__ float tile[32][33];
    int b = blockIdx.z;
    int f0 = blockIdx.x * 32, c0 = blockIdx.y * 32;
    int tx = threadIdx.x, ty = threadIdx.y;
    #pragma unroll
    for (int i = 0; i < 4; ++i) {
        int f = f0 + ty + i * 8;
        tile[ty + i * 8][tx] = cur[((size_t)b * F + f) * C + c0 + tx];
    }
    __syncthreads();
    #pragma unroll
    for (int i = 0; i < 4; ++i) {
        int c = c0 + ty + i * 8;
        out[((size_t)b * C + c) * F + f0 + tx] = tile[tx][ty + i * 8];
    }
}

// ----------------------------------------------------------------
extern "C" void kernel_launch(void* const* d_in, const int* in_sizes, int n_in,
                              void* d_out, int out_size, void* d_ws, size_t ws_size,
                              hipStream_t stream) {
    const int* levels = (const int*)d_in[15];
    int Bd = in_sizes[15] / NLV;                  // ring capacity per level

    const size_t n = (size_t)NB * F * C;          // 589824
    float* cur  = (float*)d_ws;
    float* qh   = cur + n;
    float* khT  = qh + n;
    float* vhT  = khT + n;
    float* wbuf = vhT + n;                        // fp32 weight copies, 296193 floats
    float* wT   = wbuf + 296196;                  // transposed WkT/WvT/WoT, 3*16384 floats (16B-aligned)
    int*   permIdx = (int*)(wT + 49152);
    int*   flag = permIdx + F;                    // 1 int (dtype flag)
    int*   lvflags = flag + 1;                    // 2*NLV ints (level-done flags)
    float* smS  = (float*)(permIdx + 2404);       // static softmax state: NB*F*SMH floats
    float* stgK = smS + (size_t)NB * F * SMH;     // staged K cols: NB*F*C floats
    float* stgV = stgK + n;                       // staged V cols: NB*F*C floats

    const int oWq = 0,       oWk = 16384,  oWv = 32768,  oWo = 49152;
    const int oW1 = 65536,   oB1 = 98304;
    const int oW2 = 98560,   oB2 = 164096;
    const int oW3 = 164352,  oB3 = 229888;
    const int oW4 = 230144,  oB4 = 295680;
    const int oW5 = 295936,  oB5 = 296192;
    const int wtot = 296193;

    WSegs segs = {{
        { d_in[1],  oWq, 16384 }, { d_in[2],  oWk, 16384 },
        { d_in[3],  oWv, 16384 }, { d_in[4],  oWo, 16384 },
        { d_in[5],  oW1, 32768 }, { d_in[6],  oB1, 256 },
        { d_in[7],  oW2, 65536 }, { d_in[8],  oB2, 256 },
        { d_in[9],  oW3, 65536 }, { d_in[10], oB3, 256 },
        { d_in[11], oW4, 65536 }, { d_in[12], oB4, 256 },
        { d_in[13], oW5, 256 },   { d_in[14], oB5, 1 },
    }};

    // host-side ring prefix + pair prefix (pure function of GRIDN; matches k_permdetect)
    Rings rings;
    Pairs pairs;
    int totPairs = 0;
    {
        int cnt[NLV];
        for (int l = 0; l < NLV; ++l) cnt[l] = 0;
        for (int i = 0; i < GRIDN; ++i)
            for (int j = 0; j < GRIDN; ++j)
                cnt[(i < 24 ? 24 - i : i - 24) + (j < 24 ? 24 - j : j - 24)]++;
        rings.v[0] = 0;
        pairs.v[0] = 0;
        for (int l = 0; l < NLV; ++l) {
            rings.v[l + 1] = rings.v[l] + cnt[l];
            pairs.v[l + 1] = pairs.v[l] + (cnt[l] + 1) / 2;
        }
        totPairs = pairs.v[NLV];
    }

    float* out0 = (float*)d_out;                  // final.transpose(0,2,1): [B,C,F] fp32
    float* out1 = out0 + (size_t)NB * C * F;      // scores: [B,F,1] fp32

    k_permdetect<<<1, 256, 0, stream>>>(d_in[0], flag, permIdx, lvflags);
    k_convert<<<(wtot + 255) / 256, 256, 0, stream>>>(segs, flag, wbuf, wtot);
    k_wtrans<<<dim3(C, 3), C, 0, stream>>>(wbuf + oWk, wbuf + oWv, wbuf + oWo, wT);
    k_transpose_in<<<dim3(F / 32, C / 32, NB), dim3(32, 8), 0, stream>>>(d_in[0], flag, cur);
    k_proj_init<<<(NB * F) / 2, 128, 0, stream>>>(cur, permIdx, wbuf + oWq, wbuf + oWk, wbuf + oWv,
                                                  qh, khT, vhT);

    // static partials for ALL queries at once (khT/vhT still pristine here)
    k_static<<<2 * totPairs, 256, 0, stream>>>(Bd, rings, pairs, levels, qh, khT, vhT, smS);

    // 7 launches of 7 levels each
    for (int lv0 = 0; lv0 < NLV; lv0 += GLV) {
        Grp grp;
        grp.lv0 = lv0;
        grp.rs0 = rings.v[lv0];
        grp.bofs[0] = 0;
        for (int g = 0; g < GLV; ++g) {
            int lv = lv0 + g;
            int rs = rings.v[lv], re = rings.v[lv + 1];
            int ns = (re - rs + 1) / 2;
            grp.rs[g] = rs;
            grp.re[g] = re;
            grp.ns[g] = ns;
            grp.bofs[g + 1] = grp.bofs[g] + 2 * ns;
        }
        k_group<<<grp.bofs[GLV], 256, 0, stream>>>(Bd, grp, levels, permIdx, qh, cur,
                                                   khT, vhT, smS,
                                                   wT, wT + 16384, wT + 32768,
                                                   stgK, stgV, lvflags);
    }

    k_mlp<<<(NB * F) / 2, 256, 0, stream>>>(cur, wbuf + oW1, wbuf + oB1, wbuf + oW2, wbuf + oB2,
                                            wbuf + oW3, wbuf + oB3, wbuf + oW4, wbuf + oB4,
                                            wbuf + oW5, wbuf + oB5, out1);
    k_transpose_out<<<dim3(F / 32, C / 32, NB), dim3(32, 8), 0, stream>>>(cur, out0);
}

// Round 6
// 1466.963 us; speedup vs baseline: 3.0739x; 1.0404x over previous
//
#include <hip/hip_runtime.h>
#include <hip/hip_bf16.h>
#include <stdint.h>

#define GRIDN 48
#define F 2304
#define C 128
#define H 8
#define DH 16
#define NB 2          // batch (meshes)
#define WID 256
#define NLV 49        // BFS levels for GRID=48, anchor at (24,24)
#define SMH (H * 18)  // per-face static-softmax state: 8 heads x {m, l, acc[16]}
#define GLV 7         // levels per k_group launch (49 = 7 x 7)

typedef __hip_bfloat16 bf16;

__device__ __forceinline__ float b2f(bf16 v) { return __bfloat162float(v); }

// ---------------------------------------------------------------- K0: dtype detect + BFS-ring perm + flag clear
__global__ void k_permdetect(const void* __restrict__ x, int* __restrict__ flag,
                             int* __restrict__ permIdx, int* __restrict__ lvflags) {
    __shared__ int cnt[NLV], start[NLV];
    __shared__ int bad;
    int t = threadIdx.x;
    if (t == 0) bad = 0;
    if (t < NLV) cnt[t] = 0;
    for (int i = t; i < 2 * NLV; i += 256) lvflags[i] = 0;
    __syncthreads();
    {   // dtype detect on first 2048 elements
        const bf16* xb = (const bf16*)x;
        int insane = 0;
        #pragma unroll
        for (int i = 0; i < 8; ++i) {
            float v = b2f(xb[t * 8 + i]);
            if (!(fabsf(v) < 1e10f)) insane = 1;
        }
        if (insane) atomicOr(&bad, 1);
    }
    for (int f = t; f < F; f += 256) {
        int d = abs(f / GRIDN - GRIDN / 2) + abs(f % GRIDN - GRIDN / 2);
        atomicAdd(&cnt[d], 1);
    }
    __syncthreads();
    if (t == 0) {
        int s = 0;
        for (int l = 0; l < NLV; ++l) { start[l] = s; s += cnt[l]; }
        *flag = bad;
    }
    __syncthreads();
    for (int f = t; f < F; f += 256) {
        int d = abs(f / GRIDN - GRIDN / 2) + abs(f % GRIDN - GRIDN / 2);
        permIdx[f] = atomicAdd(&start[d], 1);
    }
}

// ---------------------------------------------------------------- K0b: convert all weights/biases to fp32
struct WSeg { const void* src; int off; int cnt; };
struct WSegs { WSeg s[14]; };

__global__ void k_convert(WSegs segs, const int* __restrict__ flag,
                          float* __restrict__ dst, int total) {
    int i = blockIdx.x * blockDim.x + threadIdx.x;
    if (i >= total) return;
    bool f32 = (*flag != 0);
    #pragma unroll 1
    for (int j = 0; j < 14; ++j) {
        int off = segs.s[j].off, cnt = segs.s[j].cnt;
        if (i >= off && i < off + cnt) {
            int k = i - off;
            dst[i] = f32 ? ((const float*)segs.s[j].src)[k]
                         : b2f(((const bf16*)segs.s[j].src)[k]);
            return;
        }
    }
}

// ---------------------------------------------------------------- K0c: transposed weight copies for the epilogue
// wT[m][c][k] = W_m[k][c] for m in {Wk, Wv, Wo} -> per-output-channel rows, float4-streamable.
__global__ void k_wtrans(const float* __restrict__ Wk, const float* __restrict__ Wv,
                         const float* __restrict__ Wo, float* __restrict__ wT) {
    int m = blockIdx.y;
    const float* s = m == 0 ? Wk : (m == 1 ? Wv : Wo);
    int c = blockIdx.x;
    int k = threadIdx.x;
    wT[((size_t)m * C + c) * C + k] = s[k * C + c];
}

// ---------------------------------------------------------------- K1: x[B,C,F] -> cur[B,F,C] f32
__global__ void k_transpose_in(const void* __restrict__ x, const int* __restrict__ flag,
                               float* __restrict__ cur) {
    __shared__ float tile[32][33];
    bool f32 = (*flag != 0);
    int b = blockIdx.z;
    int f0 = blockIdx.x * 32, c0 = blockIdx.y * 32;
    int tx = threadIdx.x, ty = threadIdx.y;            // 32 x 8
    #pragma unroll
    for (int i = 0; i < 4; ++i) {
        int c = c0 + ty + i * 8;
        size_t idx = ((size_t)b * C + c) * F + f0 + tx;
        tile[ty + i * 8][tx] = f32 ? ((const float*)x)[idx] : b2f(((const bf16*)x)[idx]);
    }
    __syncthreads();
    #pragma unroll
    for (int i = 0; i < 4; ++i) {
        int f = f0 + ty + i * 8;
        cur[((size_t)b * F + f) * C + c0 + tx] = tile[tx][ty + i * 8];
    }
}

// ---------------------------------------------------------------- K2: init projections (2 rows/block for occupancy)
__global__ __launch_bounds__(128) void k_proj_init(
        const float* __restrict__ cur, const int* __restrict__ permIdx,
        const float* __restrict__ Wq, const float* __restrict__ Wk, const float* __restrict__ Wv,
        float* __restrict__ qh, float* __restrict__ khT, float* __restrict__ vhT) {
    __shared__ float rows[2][C];
    int r0 = blockIdx.x * 2;
    int tid = threadIdx.x;  // 0..127 = output channel
    rows[0][tid] = cur[(size_t)r0 * C + tid];
    rows[1][tid] = cur[(size_t)(r0 + 1) * C + tid];
    __syncthreads();
    float aq0 = 0.f, aq1 = 0.f, ak0 = 0.f, ak1 = 0.f, av0 = 0.f, av1 = 0.f;
    for (int k = 0; k < C; ++k) {
        float wq = Wq[k * C + tid];
        float wk = Wk[k * C + tid];
        float wv = Wv[k * C + tid];
        float x0 = rows[0][k], x1 = rows[1][k];
        aq0 = fmaf(x0, wq, aq0); aq1 = fmaf(x1, wq, aq1);
        ak0 = fmaf(x0, wk, ak0); ak1 = fmaf(x1, wk, ak1);
        av0 = fmaf(x0, wv, av0); av1 = fmaf(x1, wv, av1);
    }
    const float scale = 0.25f;  // 1/sqrt(DH)
    #pragma unroll
    for (int r = 0; r < 2; ++r) {
        int grow = r0 + r;
        int mesh = grow / F, face = grow % F;
        int p = permIdx[face];
        qh[(size_t)grow * C + tid] = (r == 0 ? aq0 : aq1) * scale;
        khT[((size_t)mesh * C + tid) * F + p] = r == 0 ? ak0 : ak1;
        vhT[((size_t)mesh * C + tid) * F + p] = r == 0 ? av0 : av1;
    }
}

struct Rings { int v[NLV + 1]; };
struct Pairs { int v[NLV + 1]; };

// ---------------------------------------------------------------- K2c: static attention partials.
// (unchanged — runs on pristine khT/vhT, covers key columns [rs_lv, F) per query)
__global__ __launch_bounds__(256) void k_static(
        int Bd, Rings rings, Pairs pairs,
        const int* __restrict__ levels,
        const float* __restrict__ qh_all,
        const float* __restrict__ khT, const float* __restrict__ vhT,
        float* __restrict__ smS) {
    int bx = blockIdx.x;
    int mesh = bx & 1;
    int gp = bx >> 1;
    int lv = 0;
    while (gp >= pairs.v[lv + 1]) ++lv;
    int spair = gp - pairs.v[lv];
    int rs = rings.v[lv];
    int s0 = spair * 2, s1 = s0 + 1;
    int face0 = (s0 < Bd) ? levels[lv * Bd + s0] : F;
    int face1 = (s1 < Bd) ? levels[lv * Bd + s1] : F;
    bool a0 = (face0 >= 0 && face0 < F), a1 = (face1 >= 0 && face1 < F);
    if (!a0 && !a1) return;

    __shared__ float sQh[2][C];
    int tid = threadIdx.x;
    size_t row0 = ((size_t)mesh * F + face0) * C;
    size_t row1 = ((size_t)mesh * F + face1) * C;
    if (tid < C) sQh[0][tid] = a0 ? qh_all[row0 + tid] : 0.f;
    else { int c = tid - C; sQh[1][c] = a1 ? qh_all[row1 + c] : 0.f; }
    __syncthreads();

    int head = tid >> 5, sub = tid & 31;
    float q0[DH], q1[DH];
    #pragma unroll
    for (int d = 0; d < DH; ++d) { q0[d] = sQh[0][head * DH + d]; q1[d] = sQh[1][head * DH + d]; }

    const float* Kb = khT + ((size_t)mesh * C + head * DH) * F;
    const float* Vb = vhT + ((size_t)mesh * C + head * DH) * F;

    float m0 = -1e30f, l0 = 0.f, m1 = -1e30f, l1 = 0.f;
    float acc0[DH], acc1[DH];
    #pragma unroll
    for (int d = 0; d < DH; ++d) { acc0[d] = 0.f; acc1[d] = 0.f; }

    int base0 = rs & ~127;
    for (int base = base0; base < F; base += 128) {
        int p4 = base + 4 * sub;
        float sx0 = 0, sy0 = 0, sz0 = 0, sw0 = 0;
        float sx1 = 0, sy1 = 0, sz1 = 0, sw1 = 0;
        #pragma unroll
        for (int d = 0; d < DH; ++d) {
            float4 kk = *(const float4*)(Kb + d * F + p4);
            float a = q0[d], b = q1[d];
            sx0 = fmaf(a, kk.x, sx0); sy0 = fmaf(a, kk.y, sy0);
            sz0 = fmaf(a, kk.z, sz0); sw0 = fmaf(a, kk.w, sw0);
            sx1 = fmaf(b, kk.x, sx1); sy1 = fmaf(b, kk.y, sy1);
            sz1 = fmaf(b, kk.z, sz1); sw1 = fmaf(b, kk.w, sw1);
        }
        float g0 = 1.f, g1 = 1.f, g2 = 1.f, g3 = 1.f;
        if (base < rs) {
            g0 = (p4     >= rs) ? 1.f : 0.f; g1 = (p4 + 1 >= rs) ? 1.f : 0.f;
            g2 = (p4 + 2 >= rs) ? 1.f : 0.f; g3 = (p4 + 3 >= rs) ? 1.f : 0.f;
        }
        float mx0 = fmaxf(fmaxf(sx0, sy0), fmaxf(sz0, sw0));
        float mn0 = fmaxf(m0, mx0);
        float c0 = __expf(m0 - mn0);
        float px0 = __expf(sx0 - mn0) * g0, py0 = __expf(sy0 - mn0) * g1;
        float pz0 = __expf(sz0 - mn0) * g2, pw0 = __expf(sw0 - mn0) * g3;
        l0 = fmaf(l0, c0, px0 + py0 + pz0 + pw0);
        m0 = mn0;
        float mx1 = fmaxf(fmaxf(sx1, sy1), fmaxf(sz1, sw1));
        float mn1 = fmaxf(m1, mx1);
        float c1e = __expf(m1 - mn1);
        float px1 = __expf(sx1 - mn1) * g0, py1 = __expf(sy1 - mn1) * g1;
        float pz1 = __expf(sz1 - mn1) * g2, pw1 = __expf(sw1 - mn1) * g3;
        l1 = fmaf(l1, c1e, px1 + py1 + pz1 + pw1);
        m1 = mn1;
        #pragma unroll
        for (int d = 0; d < DH; ++d) {
            float4 vv = *(const float4*)(Vb + d * F + p4);
            float w0 = fmaf(px0, vv.x, fmaf(py0, vv.y, fmaf(pz0, vv.z, pw0 * vv.w)));
            float w1 = fmaf(px1, vv.x, fmaf(py1, vv.y, fmaf(pz1, vv.z, pw1 * vv.w)));
            acc0[d] = fmaf(acc0[d], c0, w0);
            acc1[d] = fmaf(acc1[d], c1e, w1);
        }
    }

    #pragma unroll
    for (int w = 16; w >= 1; w >>= 1) {
        float mo = __shfl_xor(m0, w), lo = __shfl_xor(l0, w);
        float mn = fmaxf(m0, mo);
        float ca = __expf(m0 - mn), cb = __expf(mo - mn);
        l0 = l0 * ca + lo * cb;
        #pragma unroll
        for (int d = 0; d < DH; ++d) {
            float ao = __shfl_xor(acc0[d], w);
            acc0[d] = acc0[d] * ca + ao * cb;
        }
        m0 = mn;
        mo = __shfl_xor(m1, w); lo = __shfl_xor(l1, w);
        mn = fmaxf(m1, mo);
        ca = __expf(m1 - mn); cb = __expf(mo - mn);
        l1 = l1 * ca + lo * cb;
        #pragma unroll
        for (int d = 0; d < DH; ++d) {
            float ao = __shfl_xor(acc1[d], w);
            acc1[d] = acc1[d] * ca + ao * cb;
        }
        m1 = mn;
    }
    if (sub == 0) {
        if (a0) {
            float* S = smS + (size_t)(mesh * F + face0) * SMH + head * 18;
            S[0] = m0; S[1] = l0;
            #pragma unroll
            for (int d = 0; d < DH; ++d) S[2 + d] = acc0[d];
        }
        if (a1) {
            float* S = smS + (size_t)(mesh * F + face1) * SMH + head * 18;
            S[0] = m1; S[1] = l1;
            #pragma unroll
            for (int d = 0; d < DH; ++d) S[2 + d] = acc1[d];
        }
    }
}

// ---------------------------------------------------------------- K3: GLV BFS levels per launch.
// Flag-chained as round 5. KEY CHANGE: the flag fetch_add is RELAXED (not RELEASE) — an
// agent-scope release emits a full per-XCD L2 writeback (buffer_wbl2) on gfx95x, and up to
// 47 producer blocks per (level,mesh) were issuing that sweep every level (~20 us/link).
// Ordering is still guaranteed: stgK/stgV are written with relaxed agent-scope ATOMIC stores
// (write-through to the IF coherence point), __syncthreads() drains vmcnt(0) so they are
// complete before the flag RMW (which executes at the coherence point) is issued.
struct Grp { int lv0; int rs0; int bofs[GLV + 1]; int rs[GLV]; int re[GLV]; int ns[GLV]; };

__global__ __launch_bounds__(256, 3) void k_group(
        int Bd, Grp grp,
        const int* __restrict__ levels, const int* __restrict__ permIdx,
        const float* __restrict__ qh_all, float* __restrict__ cur,
        float* __restrict__ khT, float* __restrict__ vhT,
        const float* __restrict__ smS,
        const float* __restrict__ WkT, const float* __restrict__ WvT,
        const float* __restrict__ WoT,
        float* __restrict__ stgK, float* __restrict__ stgV,
        int* __restrict__ lvflags) {
    int bx = blockIdx.x;
    int g = 0;
    while (bx >= grp.bofs[g + 1]) ++g;            // sub-level (monotone in blockIdx)
    int lb = bx - grp.bofs[g];
    int mesh = lb & 1;
    int spair = lb >> 1;
    int lv = grp.lv0 + g;
    int rs0 = grp.rs0;

    int s0 = spair * 2, s1 = s0 + 1;
    int face0 = (s0 < Bd) ? levels[lv * Bd + s0] : F;
    int face1 = (s1 < Bd) ? levels[lv * Bd + s1] : F;
    bool a0 = (face0 >= 0 && face0 < F), a1 = (face1 >= 0 && face1 < F);

    __shared__ __attribute__((aligned(16))) float sQh[2][C], sQ[2][C], sRed[2][C], sNew2[2][C];
    __shared__ float sL[2][H];
    int tid = threadIdx.x;
    size_t row0 = ((size_t)mesh * F + face0) * C;
    size_t row1 = ((size_t)mesh * F + face1) * C;
    if (tid < C) {
        if (a0) { sQ[0][tid] = cur[row0 + tid]; sQh[0][tid] = qh_all[row0 + tid]; }
        else    { sQ[0][tid] = 0.f; sQh[0][tid] = 0.f; }
    } else {
        int c = tid - C;
        if (a1) { sQ[1][c] = cur[row1 + c]; sQh[1][c] = qh_all[row1 + c]; }
        else    { sQ[1][c] = 0.f; sQh[1][c] = 0.f; }
    }
    __syncthreads();

    int head = tid >> 5, sub = tid & 31;
    float q0[DH], q1[DH];
    #pragma unroll
    for (int d = 0; d < DH; ++d) { q0[d] = sQh[0][head * DH + d]; q1[d] = sQh[1][head * DH + d]; }

    const float* Kb = khT + ((size_t)mesh * C + head * DH) * F;
    const float* Vb = vhT + ((size_t)mesh * C + head * DH) * F;

    float m0 = -1e30f, l0 = 0.f, m1 = -1e30f, l1 = 0.f;
    float acc0[DH], acc1[DH];
    #pragma unroll
    for (int d = 0; d < DH; ++d) { acc0[d] = 0.f; acc1[d] = 0.f; }

    // ---- main stream: prior-launch columns [0, rs0)
    for (int base = 0; base < rs0; base += 128) {
        int p4 = base + 4 * sub;
        float sx0 = 0, sy0 = 0, sz0 = 0, sw0 = 0;
        float sx1 = 0, sy1 = 0, sz1 = 0, sw1 = 0;
        #pragma unroll
        for (int d = 0; d < DH; ++d) {
            float4 kk = *(const float4*)(Kb + d * F + p4);
            float a = q0[d], b = q1[d];
            sx0 = fmaf(a, kk.x, sx0); sy0 = fmaf(a, kk.y, sy0);
            sz0 = fmaf(a, kk.z, sz0); sw0 = fmaf(a, kk.w, sw0);
            sx1 = fmaf(b, kk.x, sx1); sy1 = fmaf(b, kk.y, sy1);
            sz1 = fmaf(b, kk.z, sz1); sw1 = fmaf(b, kk.w, sw1);
        }
        float g0 = 1.f, g1 = 1.f, g2 = 1.f, g3 = 1.f;
        if (base + 128 > rs0) {
            g0 = (p4     < rs0) ? 1.f : 0.f; g1 = (p4 + 1 < rs0) ? 1.f : 0.f;
            g2 = (p4 + 2 < rs0) ? 1.f : 0.f; g3 = (p4 + 3 < rs0) ? 1.f : 0.f;
        }
        float mx0 = fmaxf(fmaxf(sx0, sy0), fmaxf(sz0, sw0));
        float mn0 = fmaxf(m0, mx0);
        float c0 = __expf(m0 - mn0);
        float px0 = __expf(sx0 - mn0) * g0, py0 = __expf(sy0 - mn0) * g1;
        float pz0 = __expf(sz0 - mn0) * g2, pw0 = __expf(sw0 - mn0) * g3;
        l0 = fmaf(l0, c0, px0 + py0 + pz0 + pw0);
        m0 = mn0;
        float mx1 = fmaxf(fmaxf(sx1, sy1), fmaxf(sz1, sw1));
        float mn1 = fmaxf(m1, mx1);
        float c1e = __expf(m1 - mn1);
        float px1 = __expf(sx1 - mn1) * g0, py1 = __expf(sy1 - mn1) * g1;
        float pz1 = __expf(sz1 - mn1) * g2, pw1 = __expf(sw1 - mn1) * g3;
        l1 = fmaf(l1, c1e, px1 + py1 + pz1 + pw1);
        m1 = mn1;
        #pragma unroll
        for (int d = 0; d < DH; ++d) {
            float4 vv = *(const float4*)(Vb + d * F + p4);
            float w0 = fmaf(px0, vv.x, fmaf(py0, vv.y, fmaf(pz0, vv.z, pw0 * vv.w)));
            float w1 = fmaf(px1, vv.x, fmaf(py1, vv.y, fmaf(pz1, vv.z, pw1 * vv.w)));
            acc0[d] = fmaf(acc0[d], c0, w0);
            acc1[d] = fmaf(acc1[d], c1e, w1);
        }
    }

    // ---- staged folds: same-launch columns [rs0, rs_lv), sub-level by sub-level
    for (int gp = 0; gp < g; ++gp) {
        if (tid == 0) {
            int need = grp.ns[gp];
            int* fl = &lvflags[(grp.lv0 + gp) * 2 + mesh];
            int guard = 0;
            while (__hip_atomic_load(fl, __ATOMIC_RELAXED, __HIP_MEMORY_SCOPE_AGENT) < need
                   && guard < (1 << 22)) {
                __builtin_amdgcn_s_sleep(1);
                ++guard;
            }
        }
        __syncthreads();                           // all lanes ordered after flag observation
        int frs = grp.rs[gp], fre = grp.re[gp];
        for (int p = frs + sub; p < fre; p += 32) {
            const unsigned long long* kc =
                (const unsigned long long*)(stgK + ((size_t)mesh * F + p) * C + head * DH);
            const unsigned long long* vc =
                (const unsigned long long*)(stgV + ((size_t)mesh * F + p) * C + head * DH);
            float s0v = 0.f, s1v = 0.f;
            #pragma unroll
            for (int d2 = 0; d2 < DH / 2; ++d2) {
                unsigned long long kw = __hip_atomic_load(kc + d2, __ATOMIC_RELAXED,
                                                          __HIP_MEMORY_SCOPE_AGENT);
                float2 kf = *(float2*)&kw;
                s0v = fmaf(q0[2 * d2], kf.x, s0v); s0v = fmaf(q0[2 * d2 + 1], kf.y, s0v);
                s1v = fmaf(q1[2 * d2], kf.x, s1v); s1v = fmaf(q1[2 * d2 + 1], kf.y, s1v);
            }
            float vv[DH];
            #pragma unroll
            for (int d2 = 0; d2 < DH / 2; ++d2) {
                unsigned long long vw = __hip_atomic_load(vc + d2, __ATOMIC_RELAXED,
                                                          __HIP_MEMORY_SCOPE_AGENT);
                float2 vf = *(float2*)&vw;
                vv[2 * d2] = vf.x; vv[2 * d2 + 1] = vf.y;
            }
            {   // fold query 0
                float mn = fmaxf(m0, s0v);
                float c = __expf(m0 - mn), pw = __expf(s0v - mn);
                l0 = l0 * c + pw;
                #pragma unroll
                for (int d = 0; d < DH; ++d) acc0[d] = fmaf(acc0[d], c, pw * vv[d]);
                m0 = mn;
            }
            {   // fold query 1
                float mn = fmaxf(m1, s1v);
                float c = __expf(m1 - mn), pw = __expf(s1v - mn);
                l1 = l1 * c + pw;
                #pragma unroll
                for (int d = 0; d < DH; ++d) acc1[d] = fmaf(acc1[d], c, pw * vv[d]);
                m1 = mn;
            }
        }
    }

    // ---- merge 32 per-lane states per head
    #pragma unroll
    for (int w = 16; w >= 1; w >>= 1) {
        float mo = __shfl_xor(m0, w), lo = __shfl_xor(l0, w);
        float mn = fmaxf(m0, mo);
        float ca = __expf(m0 - mn), cb = __expf(mo - mn);
        l0 = l0 * ca + lo * cb;
        #pragma unroll
        for (int d = 0; d < DH; ++d) {
            float ao = __shfl_xor(acc0[d], w);
            acc0[d] = acc0[d] * ca + ao * cb;
        }
        m0 = mn;
        mo = __shfl_xor(m1, w); lo = __shfl_xor(l1, w);
        mn = fmaxf(m1, mo);
        ca = __expf(m1 - mn); cb = __expf(mo - mn);
        l1 = l1 * ca + lo * cb;
        #pragma unroll
        for (int d = 0; d < DH; ++d) {
            float ao = __shfl_xor(acc1[d], w);
            acc1[d] = acc1[d] * ca + ao * cb;
        }
        m1 = mn;
    }
    if (sub == 0) {
        // merge with the precomputed static state over [rs_lv, F)
        {
            int fr = a0 ? face0 : 0;
            const float* S = smS + (size_t)(mesh * F + fr) * SMH + head * 18;
            float ms = S[0], ls = S[1];
            float mn = fmaxf(m0, ms);
            float ca = __expf(m0 - mn), cb = __expf(ms - mn);
            sL[0][head] = l0 * ca + ls * cb;
            #pragma unroll
            for (int d = 0; d < DH; ++d)
                sRed[0][head * DH + d] = fmaf(acc0[d], ca, S[2 + d] * cb);
        }
        {
            int fr = a1 ? face1 : 0;
            const float* S = smS + (size_t)(mesh * F + fr) * SMH + head * 18;
            float ms = S[0], ls = S[1];
            float mn = fmaxf(m1, ms);
            float ca = __expf(m1 - mn), cb = __expf(ms - mn);
            sL[1][head] = l1 * ca + ls * cb;
            #pragma unroll
            for (int d = 0; d < DH; ++d)
                sRed[1][head * DH + d] = fmaf(acc1[d], ca, S[2 + d] * cb);
        }
    }
    __syncthreads();
    if (tid < C) sRed[0][tid] = sRed[0][tid] / sL[0][tid >> 4];
    else { int c = tid - C; sRed[1][c] = sRed[1][c] / sL[1][c >> 4]; }
    __syncthreads();

    // ---- epilogue (transposed weights): E1 out-proj + resid for BOTH queries in parallel,
    //      then per-query K/V refresh with K and V halves in parallel.
    bool doStage = (g != GLV - 1);
    {
        int j = tid >> 7;              // which query this half handles
        int c = tid & 127;
        bool act = j == 0 ? a0 : a1;
        float o = 0.f;
        const float4* WoR = (const float4*)(WoT + (size_t)c * C);
        const float4* Rr  = (const float4*)(&sRed[j][0]);
        #pragma unroll
        for (int k4 = 0; k4 < C / 4; ++k4) {
            float4 w = WoR[k4];
            float4 r = Rr[k4];
            o = fmaf(r.x, w.x, o); o = fmaf(r.y, w.y, o);
            o = fmaf(r.z, w.z, o); o = fmaf(r.w, w.w, o);
        }
        float nv = sQ[j][c] + o;
        sNew2[j][c] = nv;
        if (act) cur[(j == 0 ? row0 : row1) + c] = nv;
    }
    __syncthreads();
    #pragma unroll 1
    for (int j = 0; j < 2; ++j) {
        bool act = j == 0 ? a0 : a1;
        if (!act) continue;
        int facej = j == 0 ? face0 : face1;
        int p = permIdx[facej];
        int c = tid & 127;
        const float* WT = (tid < C) ? WkT : WvT;
        float a = 0.f;
        const float4* Wr = (const float4*)(WT + (size_t)c * C);
        const float4* Nr = (const float4*)(&sNew2[j][0]);
        #pragma unroll
        for (int k4 = 0; k4 < C / 4; ++k4) {
            float4 w = Wr[k4];
            float4 x = Nr[k4];
            a = fmaf(x.x, w.x, a); a = fmaf(x.y, w.y, a);
            a = fmaf(x.z, w.z, a); a = fmaf(x.w, w.w, a);
        }
        if (tid < C) {
            khT[((size_t)mesh * C + c) * F + p] = a;
            if (doStage)
                __hip_atomic_store(stgK + ((size_t)mesh * F + p) * C + c, a,
                                   __ATOMIC_RELAXED, __HIP_MEMORY_SCOPE_AGENT);
        } else {
            vhT[((size_t)mesh * C + c) * F + p] = a;
            if (doStage)
                __hip_atomic_store(stgV + ((size_t)mesh * F + p) * C + c, a,
                                   __ATOMIC_RELAXED, __HIP_MEMORY_SCOPE_AGENT);
        }
    }
    __syncthreads();                               // drains all waves' stores (vmcnt 0) before flag
    if (doStage && tid == 0)
        __hip_atomic_fetch_add(&lvflags[lv * 2 + mesh], 1,
                               __ATOMIC_RELAXED, __HIP_MEMORY_SCOPE_AGENT);
}

// ---------------------------------------------------------------- K4: 5-layer MLP + sigmoid (2 rows/block)
__global__ __launch_bounds__(256) void k_mlp(
        const float* __restrict__ cur,
        const float* __restrict__ W1, const float* __restrict__ b1,
        const float* __restrict__ W2, const float* __restrict__ b2,
        const float* __restrict__ W3, const float* __restrict__ b3,
        const float* __restrict__ W4, const float* __restrict__ b4,
        const float* __restrict__ W5, const float* __restrict__ b5,
        float* __restrict__ out_scores) {
    __shared__ float sIn[2][C];
    __shared__ float sA[2][WID];
    __shared__ float sB[2][WID];
    int tid = threadIdx.x;                        // 0..255
    int r0 = blockIdx.x * 2;
    for (int i = tid; i < 2 * C; i += 256) sIn[i >> 7][i & 127] = cur[(size_t)r0 * C + i];
    __syncthreads();
    {
        float a0 = 0.f, a1 = 0.f;
        for (int k = 0; k < C; ++k) {
            float w = W1[k * WID + tid];
            a0 = fmaf(sIn[0][k], w, a0);
            a1 = fmaf(sIn[1][k], w, a1);
        }
        float bias = b1[tid];
        sA[0][tid] = fmaxf(a0 + bias, 0.f);
        sA[1][tid] = fmaxf(a1 + bias, 0.f);
    }
    __syncthreads();
    {
        float a0 = 0.f, a1 = 0.f;
        for (int k = 0; k < WID; ++k) {
            float w = W2[k * WID + tid];
            a0 = fmaf(sA[0][k], w, a0);
            a1 = fmaf(sA[1][k], w, a1);
        }
        float bias = b2[tid];
        sB[0][tid] = fmaxf(a0 + bias, 0.f);
        sB[1][tid] = fmaxf(a1 + bias, 0.f);
    }
    __syncthreads();
    {
        float a0 = 0.f, a1 = 0.f;
        for (int k = 0; k < WID; ++k) {
            float w = W3[k * WID + tid];
            a0 = fmaf(sB[0][k], w, a0);
            a1 = fmaf(sB[1][k], w, a1);
        }
        float bias = b3[tid];
        sA[0][tid] = fmaxf(a0 + bias, 0.f);
        sA[1][tid] = fmaxf(a1 + bias, 0.f);
    }
    __syncthreads();
    {
        float a0 = 0.f, a1 = 0.f;
        for (int k = 0; k < WID; ++k) {
            float w = W4[k * WID + tid];
            a0 = fmaf(sA[0][k], w, a0);
            a1 = fmaf(sA[1][k], w, a1);
        }
        float bias = b4[tid];
        sB[0][tid] = fmaxf(a0 + bias, 0.f);
        sB[1][tid] = fmaxf(a1 + bias, 0.f);
    }
    __syncthreads();
    if (tid < 2) {
        float a = b5[0];
        for (int k = 0; k < WID; ++k) a = fmaf(sB[tid][k], W5[k], a);
        out_scores[r0 + tid] = 1.f / (1.f + __expf(-a));
    }
}

// ---------------------------------------------------------------- K5: cur[B,F,C] f32 -> out0[B,C,F] f32
__global__ void k_transpose_out(const float* __restrict__ cur, float* __restrict__ out) {
    __shared__ float tile[32][33];
    int b = blockIdx.z;
    int f0 = blockIdx.x * 32, c0 = blockIdx.y * 32;
    int tx = threadIdx.x, ty = threadIdx.y;
    #pragma unroll
    for (int i = 0; i < 4; ++i) {
        int f = f0 + ty + i * 8;
        tile[ty + i * 8][tx] = cur[((size_t)b * F + f) * C + c0 + tx];
    }
    __syncthreads();
    #pragma unroll
    for (int i = 0; i < 4; ++i) {
        int c = c0 + ty + i * 8;
        out[((size_t)b * C + c) * F + f0 + tx] = tile[tx][ty + i * 8];
    }
}

// ----------------------------------------------------------------
extern "C" void kernel_launch(void* const* d_in, const int* in_sizes, int n_in,
                              void* d_out, int out_size, void* d_ws, size_t ws_size,
                              hipStream_t stream) {
    const int* levels = (const int*)d_in[15];
    int Bd = in_sizes[15] / NLV;                  // ring capacity per level

    const size_t n = (size_t)NB * F * C;          // 589824
    float* cur  = (float*)d_ws;
    float* qh   = cur + n;
    float* khT  = qh + n;
    float* vhT  = khT + n;
    float* wbuf = vhT + n;                        // fp32 weight copies, 296193 floats
    float* wT   = wbuf + 296196;                  // transposed WkT/WvT/WoT, 3*16384 floats (16B-aligned)
    int*   permIdx = (int*)(wT + 49152);
    int*   flag = permIdx + F;                    // 1 int (dtype flag)
    int*   lvflags = flag + 1;                    // 2*NLV ints (level-done flags)
    float* smS  = (float*)(permIdx + 2404);       // static softmax state: NB*F*SMH floats
    float* stgK = smS + (size_t)NB * F * SMH;     // staged K cols: NB*F*C floats
    float* stgV = stgK + n;                       // staged V cols: NB*F*C floats

    const int oWq = 0,       oWk = 16384,  oWv = 32768,  oWo = 49152;
    const int oW1 = 65536,   oB1 = 98304;
    const int oW2 = 98560,   oB2 = 164096;
    const int oW3 = 164352,  oB3 = 229888;
    const int oW4 = 230144,  oB4 = 295680;
    const int oW5 = 295936,  oB5 = 296192;
    const int wtot = 296193;

    WSegs segs = {{
        { d_in[1],  oWq, 16384 }, { d_in[2],  oWk, 16384 },
        { d_in[3],  oWv, 16384 }, { d_in[4],  oWo, 16384 },
        { d_in[5],  oW1, 32768 }, { d_in[6],  oB1, 256 },
        { d_in[7],  oW2, 65536 }, { d_in[8],  oB2, 256 },
        { d_in[9],  oW3, 65536 }, { d_in[10], oB3, 256 },
        { d_in[11], oW4, 65536 }, { d_in[12], oB4, 256 },
        { d_in[13], oW5, 256 },   { d_in[14], oB5, 1 },
    }};

    // host-side ring prefix + pair prefix (pure function of GRIDN; matches k_permdetect)
    Rings rings;
    Pairs pairs;
    int totPairs = 0;
    {
        int cnt[NLV];
        for (int l = 0; l < NLV; ++l) cnt[l] = 0;
        for (int i = 0; i < GRIDN; ++i)
            for (int j = 0; j < GRIDN; ++j)
                cnt[(i < 24 ? 24 - i : i - 24) + (j < 24 ? 24 - j : j - 24)]++;
        rings.v[0] = 0;
        pairs.v[0] = 0;
        for (int l = 0; l < NLV; ++l) {
            rings.v[l + 1] = rings.v[l] + cnt[l];
            pairs.v[l + 1] = pairs.v[l] + (cnt[l] + 1) / 2;
        }
        totPairs = pairs.v[NLV];
    }

    float* out0 = (float*)d_out;                  // final.transpose(0,2,1): [B,C,F] fp32
    float* out1 = out0 + (size_t)NB * C * F;      // scores: [B,F,1] fp32

    k_permdetect<<<1, 256, 0, stream>>>(d_in[0], flag, permIdx, lvflags);
    k_convert<<<(wtot + 255) / 256, 256, 0, stream>>>(segs, flag, wbuf, wtot);
    k_wtrans<<<dim3(C, 3), C, 0, stream>>>(wbuf + oWk, wbuf + oWv, wbuf + oWo, wT);
    k_transpose_in<<<dim3(F / 32, C / 32, NB), dim3(32, 8), 0, stream>>>(d_in[0], flag, cur);
    k_proj_init<<<(NB * F) / 2, 128, 0, stream>>>(cur, permIdx, wbuf + oWq, wbuf + oWk, wbuf + oWv,
                                                  qh, khT, vhT);

    // static partials for ALL queries at once (khT/vhT still pristine here)
    k_static<<<2 * totPairs, 256, 0, stream>>>(Bd, rings, pairs, levels, qh, khT, vhT, smS);

    // 7 launches of 7 levels each
    for (int lv0 = 0; lv0 < NLV; lv0 += GLV) {
        Grp grp;
        grp.lv0 = lv0;
        grp.rs0 = rings.v[lv0];
        grp.bofs[0] = 0;
        for (int g = 0; g < GLV; ++g) {
            int lv = lv0 + g;
            int rs = rings.v[lv], re = rings.v[lv + 1];
            int ns = (re - rs + 1) / 2;
            grp.rs[g] = rs;
            grp.re[g] = re;
            grp.ns[g] = ns;
            grp.bofs[g + 1] = grp.bofs[g] + 2 * ns;
        }
        k_group<<<grp.bofs[GLV], 256, 0, stream>>>(Bd, grp, levels, permIdx, qh, cur,
                                                   khT, vhT, smS,
                                                   wT, wT + 16384, wT + 32768,
                                                   stgK, stgV, lvflags);
    }

    k_mlp<<<(NB * F) / 2, 256, 0, stream>>>(cur, wbuf + oW1, wbuf + oB1, wbuf + oW2, wbuf + oB2,
                                            wbuf + oW3, wbuf + oB3, wbuf + oW4, wbuf + oB4,
                                            wbuf + oW5, wbuf + oB5, out1);
    k_transpose_out<<<dim3(F / 32, C / 32, NB), dim3(32, 8), 0, stream>>>(cur, out0);
}